// Round 10
// baseline (774.892 us; speedup 1.0000x reference)
//
#include <hip/hip_runtime.h>

#define N_NODES 100000
#define N_EDGES 1600000
#define DIM 64

#define BIN_SHIFT 8
#define BIN_NODES 256
#define NBINS ((N_NODES + BIN_NODES - 1) / BIN_NODES)   // 391
#define GB_PAD 66                                        // acc row stride (words)

#define TILE_A 8192
#define EPB (TILE_A / 256)                               // 32 edges/thread
#define NBLK_A ((N_EDGES + TILE_A - 1) / TILE_A)         // 196

typedef __attribute__((ext_vector_type(8))) short bf16x8;
typedef __attribute__((ext_vector_type(4))) float f32x4;

// ---- bf16 helpers (hand-rolled, RNE; inputs are finite) --------------------
__device__ __forceinline__ float bflo(unsigned u) { return __uint_as_float(u << 16); }
__device__ __forceinline__ float bfhi(unsigned u) { return __uint_as_float(u & 0xFFFF0000u); }
__device__ __forceinline__ unsigned f2bf(float f) {
    unsigned u = __float_as_uint(f);
    u += 0x7FFFu + ((u >> 16) & 1u);
    return u >> 16;
}

// ---------------------------------------------------------------------------
// prep: rx = relu(x) as bf16, packed. 4 floats / thread.
// ---------------------------------------------------------------------------
__global__ __launch_bounds__(256) void prep_relu(
    const float* __restrict__ x, unsigned* __restrict__ rx)
{
    const int i = blockIdx.x * blockDim.x + threadIdx.x;
    if (i >= N_NODES * DIM / 4) return;
    const float4 v = reinterpret_cast<const float4*>(x)[i];
    uint2 o;
    o.x = f2bf(fmaxf(v.x, 0.f)) | (f2bf(fmaxf(v.y, 0.f)) << 16);
    o.y = f2bf(fmaxf(v.z, 0.f)) | (f2bf(fmaxf(v.w, 0.f)) << 16);
    reinterpret_cast<uint2*>(rx)[i] = o;
}

// ---------------------------------------------------------------------------
// wprep: prepack W1,W2 into MFMA B-frag lane order, bf16.
// ---------------------------------------------------------------------------
__global__ __launch_bounds__(256) void wprep(
    const float* __restrict__ W1, const float* __restrict__ W2,
    unsigned short* __restrict__ Wpk)
{
    const int idx = blockIdx.x * 256 + threadIdx.x;
    if (idx >= 8192) return;
    const int j    = idx & 7;
    const int lane = (idx >> 3) & 63;
    const int kk   = (idx >> 9) & 1;
    const int n    = (idx >> 10) & 3;
    const int L    = idx >> 12;
    const float* W = L ? W2 : W1;
    const int k    = kk * 32 + (lane >> 4) * 8 + j;
    const int col  = n * 16 + (lane & 15);
    Wpk[idx] = (unsigned short)f2bf(W[k * DIM + col]);
}

// ---------------------------------------------------------------------------
// bincount: coarse-bin histogram via LDS aggregation (391 bins of 256 nodes).
// ---------------------------------------------------------------------------
__global__ __launch_bounds__(256) void bincount(
    const int* __restrict__ ei, int* __restrict__ binc)
{
    __shared__ int lh[NBINS];
    for (int i = threadIdx.x; i < NBINS; i += 256) lh[i] = 0;
    __syncthreads();
    const int t = blockIdx.x * blockDim.x + threadIdx.x;
    const int e = t * 4;
    if (e + 3 < N_EDGES) {
        const int4 d4 = *reinterpret_cast<const int4*>(ei + N_EDGES + e);
        atomicAdd(&lh[d4.x >> BIN_SHIFT], 1);
        atomicAdd(&lh[d4.y >> BIN_SHIFT], 1);
        atomicAdd(&lh[d4.z >> BIN_SHIFT], 1);
        atomicAdd(&lh[d4.w >> BIN_SHIFT], 1);
    } else {
        for (int k = e; k < N_EDGES; ++k)
            atomicAdd(&lh[ei[N_EDGES + k] >> BIN_SHIFT], 1);
    }
    __syncthreads();
    for (int i = threadIdx.x; i < NBINS; i += 256)
        if (lh[i]) atomicAdd(&binc[i], lh[i]);
}

// ---------------------------------------------------------------------------
// binscan: single block, 2-per-thread exclusive scan of 391 bin counts
// -> binbase[392]; seeds gcur.
// ---------------------------------------------------------------------------
__global__ __launch_bounds__(256) void binscan(
    const int* __restrict__ binc, int* __restrict__ binbase,
    int* __restrict__ gcur)
{
    __shared__ int ls[256];
    const int t = threadIdx.x;
    const int a0 = (2 * t     < NBINS) ? binc[2 * t]     : 0;
    const int a1 = (2 * t + 1 < NBINS) ? binc[2 * t + 1] : 0;
    const int ps = a0 + a1;
    ls[t] = ps;
    __syncthreads();
    #pragma unroll
    for (int d = 1; d < 256; d <<= 1) {
        const int add = (t >= d) ? ls[t - d] : 0;
        __syncthreads();
        ls[t] += add;
        __syncthreads();
    }
    const int pb = ls[t] - ps;
    if (2 * t < NBINS)     { binbase[2 * t]     = pb;      gcur[2 * t]     = pb; }
    if (2 * t + 1 < NBINS) { binbase[2 * t + 1] = pb + a0; gcur[2 * t + 1] = pb + a0; }
    if (t == 0) binbase[NBINS] = N_EDGES;
}

// ---------------------------------------------------------------------------
// binscatter: block stages TILE_A=8192 edges in LDS grouped by bin (dst>>8),
// allocates one contiguous run per bin (global atomic on gcur), streams out
// packed entries (src<<8 | dst&255). Runs avg ~21 entries (84 B).
// ---------------------------------------------------------------------------
__global__ __launch_bounds__(256) void binscatter(
    const int* __restrict__ ei,
    int* __restrict__ gcur,
    unsigned* __restrict__ binned)
{
    __shared__ int lhist[NBINS];
    __shared__ int lbase[NBINS];
    __shared__ int lcur[NBINS];
    __shared__ int ldelta[NBINS];
    __shared__ int ls[256];
    __shared__ unsigned staged[TILE_A];
    __shared__ unsigned short sbin[TILE_A];

    const int t  = threadIdx.x;
    const int e0 = blockIdx.x * TILE_A;
    const int n  = min(TILE_A, N_EDGES - e0);

    for (int i = t; i < NBINS; i += 256) { lhist[i] = 0; lcur[i] = 0; }
    __syncthreads();

    int      mybin[EPB];
    unsigned myval[EPB];
    #pragma unroll
    for (int j = 0; j < EPB; ++j) {
        const int idx = t + j * 256;
        if (idx < n) {
            const int s = ei[e0 + idx];
            const int d = ei[N_EDGES + e0 + idx];
            mybin[j] = d >> BIN_SHIFT;
            myval[j] = ((unsigned)s << BIN_SHIFT) | (unsigned)(d & (BIN_NODES - 1));
            atomicAdd(&lhist[mybin[j]], 1);
        } else {
            mybin[j] = -1;
        }
    }
    __syncthreads();

    // 2-per-thread exclusive scan of lhist[0..390] -> lbase
    const int a0 = (2 * t     < NBINS) ? lhist[2 * t]     : 0;
    const int a1 = (2 * t + 1 < NBINS) ? lhist[2 * t + 1] : 0;
    const int ps = a0 + a1;
    ls[t] = ps;
    __syncthreads();
    #pragma unroll
    for (int d = 1; d < 256; d <<= 1) {
        const int add = (t >= d) ? ls[t - d] : 0;
        __syncthreads();
        ls[t] += add;
        __syncthreads();
    }
    const int pb = ls[t] - ps;
    if (2 * t < NBINS)     lbase[2 * t]     = pb;
    if (2 * t + 1 < NBINS) lbase[2 * t + 1] = pb + a0;
    __syncthreads();

    // allocate global runs
    for (int i = t; i < NBINS; i += 256) {
        const int c = lhist[i];
        ldelta[i] = (c > 0) ? (atomicAdd(&gcur[i], c) - lbase[i]) : 0;
    }
    __syncthreads();

    // stage into LDS grouped by bin
    #pragma unroll
    for (int j = 0; j < EPB; ++j) {
        if (mybin[j] >= 0) {
            const int p = lbase[mybin[j]] + atomicAdd(&lcur[mybin[j]], 1);
            staged[p] = myval[j];
            sbin[p]   = (unsigned short)mybin[j];
        }
    }
    __syncthreads();

    for (int p = t; p < n; p += 256)
        binned[p + ldelta[sbin[p]]] = staged[p];
}

// ---------------------------------------------------------------------------
// bin_gather: one block per 256-node bin. LDS f32 accumulators (row stride 66
// words -> per-dst bank skew, ~2-way). Each wave: 64-entry coalesced chunk,
// 8-lane subgroup per edge, 8 rx-rows (128 B each) in flight, native
// ds_add_f32 accumulate. Epilogue: h = x + acc -> hbuf (bf16 pairs).
// Replaces binsort + slot[] + the wave-per-node gather.
// ---------------------------------------------------------------------------
__global__ __launch_bounds__(512) void bin_gather(
    const float*  __restrict__ x,
    const unsigned char* __restrict__ rx,     // bf16 rows, 128 B each
    const unsigned* __restrict__ binned,
    const int* __restrict__ binbase,
    unsigned* __restrict__ hbuf)
{
    __shared__ float acc[BIN_NODES * GB_PAD];  // 256*66*4 = 67584 B

    const int b     = blockIdx.x;
    const int node0 = b << BIN_SHIFT;
    const int nloc  = min(BIN_NODES, N_NODES - node0);
    const int base  = binbase[b];
    const int cnt   = binbase[b + 1] - base;
    const int t     = threadIdx.x;
    const int lane  = t & 63;

    for (int i = t; i < BIN_NODES * GB_PAD; i += 512) acc[i] = 0.f;
    __syncthreads();

    const int sg = lane >> 3;        // edge subgroup 0..7
    const int c  = lane & 7;         // 16B chunk of the 128B row

    for (int pb = (t >> 6) * 64; pb < cnt; pb += 512) {
        const int nv = min(64, cnt - pb);
        const unsigned my = (lane < nv) ? binned[base + pb + lane] : 0u;

        uint4 buf[8];
        unsigned ent[8];
        #pragma unroll
        for (int k = 0; k < 8; ++k) {
            const int ep = k * 8 + sg;
            ent[k] = (unsigned)__shfl((int)my, ep, 64);
            if (ep < nv) {
                const unsigned src = ent[k] >> BIN_SHIFT;
                buf[k] = *reinterpret_cast<const uint4*>(
                    rx + (size_t)src * 128 + c * 16);
            }
        }
        #pragma unroll
        for (int k = 0; k < 8; ++k) {
            const int ep = k * 8 + sg;
            if (ep < nv) {
                const int dstl = (int)(ent[k] & (BIN_NODES - 1));
                float* ap = &acc[dstl * GB_PAD + c * 8];
                unsafeAtomicAdd(ap + 0, bflo(buf[k].x));
                unsafeAtomicAdd(ap + 1, bfhi(buf[k].x));
                unsafeAtomicAdd(ap + 2, bflo(buf[k].y));
                unsafeAtomicAdd(ap + 3, bfhi(buf[k].y));
                unsafeAtomicAdd(ap + 4, bflo(buf[k].z));
                unsafeAtomicAdd(ap + 5, bfhi(buf[k].z));
                unsafeAtomicAdd(ap + 6, bflo(buf[k].w));
                unsafeAtomicAdd(ap + 7, bfhi(buf[k].w));
            }
        }
    }
    __syncthreads();

    // h = x + acc, packed bf16 pairs, coalesced
    for (int i = t; i < nloc * 32; i += 512) {
        const int nl = i >> 5;
        const int dp = i & 31;
        const float2 xv = *reinterpret_cast<const float2*>(
            x + (size_t)(node0 + nl) * DIM + dp * 2);
        const float2 av = *reinterpret_cast<const float2*>(
            &acc[nl * GB_PAD + dp * 2]);
        const float h0 = xv.x + av.x;
        const float h1 = xv.y + av.y;
        hbuf[(size_t)(node0 + nl) * 32 + dp] = f2bf(h0) | (f2bf(h1) << 16);
    }
}

// ---------------------------------------------------------------------------
// mlp_mfma: per wave, 16 nodes; two MFMA GEMMs, fused bias+relu (unchanged).
// ---------------------------------------------------------------------------
__global__ __launch_bounds__(256) void mlp_mfma(
    const unsigned* __restrict__ hbuf,       // bf16 rows, 128 B each
    const unsigned short* __restrict__ Wpk,  // prepacked B-frags
    const float* __restrict__ b1,
    const float* __restrict__ b2,
    float* __restrict__ out)
{
    __shared__ float yt[4][16 * 68];

    const int wiv  = threadIdx.x >> 6;
    const int lane = threadIdx.x & 63;
    const int wid  = blockIdx.x * 4 + wiv;
    const int r0   = wid * 16;
    if (r0 >= N_NODES) return;

    const int lrow = lane & 15;
    const int lgrp = lane >> 4;

    const int hrow = min(r0 + lrow, N_NODES - 1);
    const uint4* hrowp =
        reinterpret_cast<const uint4*>((const char*)hbuf + (size_t)hrow * 128);
    union UF { uint4 u; bf16x8 v; };
    UF ha0, ha1;
    ha0.u = hrowp[lgrp];
    ha1.u = hrowp[lgrp + 4];

    const uint4* wp = reinterpret_cast<const uint4*>(Wpk);

    float* my = &yt[wiv][0];
    #pragma unroll
    for (int n = 0; n < 4; ++n) {
        const float bi = b1[n * 16 + lrow];
        f32x4 acc = {bi, bi, bi, bi};
        UF bw0, bw1;
        bw0.u = wp[(n * 2 + 0) * 64 + lane];
        bw1.u = wp[(n * 2 + 1) * 64 + lane];
        acc = __builtin_amdgcn_mfma_f32_16x16x32_bf16(ha0.v, bw0.v, acc, 0, 0, 0);
        acc = __builtin_amdgcn_mfma_f32_16x16x32_bf16(ha1.v, bw1.v, acc, 0, 0, 0);
        #pragma unroll
        for (int i = 0; i < 4; ++i)
            my[(lgrp * 4 + i) * 68 + n * 16 + lrow] = fmaxf(acc[i], 0.f);
    }

    const float* yr = &yt[wiv][lrow * 68 + lgrp * 8];
    const float4 p0 = *reinterpret_cast<const float4*>(yr + 0);
    const float4 p1 = *reinterpret_cast<const float4*>(yr + 4);
    const float4 p2 = *reinterpret_cast<const float4*>(yr + 32);
    const float4 p3 = *reinterpret_cast<const float4*>(yr + 36);

    union UB { bf16x8 v; unsigned short s[8]; };
    UB ya0, ya1;
    ya0.s[0] = (unsigned short)f2bf(p0.x); ya0.s[1] = (unsigned short)f2bf(p0.y);
    ya0.s[2] = (unsigned short)f2bf(p0.z); ya0.s[3] = (unsigned short)f2bf(p0.w);
    ya0.s[4] = (unsigned short)f2bf(p1.x); ya0.s[5] = (unsigned short)f2bf(p1.y);
    ya0.s[6] = (unsigned short)f2bf(p1.z); ya0.s[7] = (unsigned short)f2bf(p1.w);
    ya1.s[0] = (unsigned short)f2bf(p2.x); ya1.s[1] = (unsigned short)f2bf(p2.y);
    ya1.s[2] = (unsigned short)f2bf(p2.z); ya1.s[3] = (unsigned short)f2bf(p2.w);
    ya1.s[4] = (unsigned short)f2bf(p3.x); ya1.s[5] = (unsigned short)f2bf(p3.y);
    ya1.s[6] = (unsigned short)f2bf(p3.z); ya1.s[7] = (unsigned short)f2bf(p3.w);

    #pragma unroll
    for (int n = 0; n < 4; ++n) {
        const float bi = b2[n * 16 + lrow];
        f32x4 acc = {bi, bi, bi, bi};
        UF bw0, bw1;
        bw0.u = wp[(8 + n * 2 + 0) * 64 + lane];
        bw1.u = wp[(8 + n * 2 + 1) * 64 + lane];
        acc = __builtin_amdgcn_mfma_f32_16x16x32_bf16(ya0.v, bw0.v, acc, 0, 0, 0);
        acc = __builtin_amdgcn_mfma_f32_16x16x32_bf16(ya1.v, bw1.v, acc, 0, 0, 0);
        #pragma unroll
        for (int i = 0; i < 4; ++i) {
            const int r = r0 + lgrp * 4 + i;
            if (r < N_NODES)
                out[(size_t)r * DIM + n * 16 + lrow] = fmaxf(acc[i], 0.f);
        }
    }
}

// ---------------------------------------------------------------------------
extern "C" void kernel_launch(void* const* d_in, const int* in_sizes, int n_in,
                              void* d_out, int out_size, void* d_ws, size_t ws_size,
                              hipStream_t stream) {
    const float* x  = (const float*)d_in[0];
    const int*   ei = (const int*)d_in[1];
    const float* W1 = (const float*)d_in[2];
    const float* b1 = (const float*)d_in[3];
    const float* W2 = (const float*)d_in[4];
    const float* b2 = (const float*)d_in[5];
    float* out = (float*)d_out;

    // rx (relu(x) in bf16, 12.8 MB) lives in d_out; fully consumed by
    // bin_gather before mlp_mfma overwrites d_out.
    unsigned* rx = (unsigned*)d_out;

    // workspace: binc | binbase | gcur | binned | hbuf | Wpk  (~19.2 MB)
    int* binc    = (int*)d_ws;                 // 391 (pad 512)
    int* binbase = binc + 512;                 // 392 (pad 512)
    int* gcur    = binbase + 512;              // 391 (pad 512)
    unsigned* binned = (unsigned*)(gcur + 512);          // N_EDGES
    unsigned* hbuf   = binned + N_EDGES;                 // N_NODES*32 uints
    unsigned short* Wpk =
        (unsigned short*)(hbuf + (size_t)N_NODES * 32);  // 8192 bf16

    hipMemsetAsync(binc, 0, NBINS * sizeof(int), stream);

    prep_relu<<<(N_NODES * DIM / 4 + 255) / 256, 256, 0, stream>>>(x, rx);
    wprep<<<32, 256, 0, stream>>>(W1, W2, Wpk);

    const int eblocks4 = (N_EDGES / 4 + 255) / 256;
    bincount<<<eblocks4, 256, 0, stream>>>(ei, binc);
    binscan<<<1, 256, 0, stream>>>(binc, binbase, gcur);
    binscatter<<<NBLK_A, 256, 0, stream>>>(ei, gcur, binned);

    bin_gather<<<NBINS, 512, 0, stream>>>(
        x, (const unsigned char*)rx, binned, binbase, hbuf);

    mlp_mfma<<<(N_NODES + 63) / 64, 256, 0, stream>>>(
        hbuf, Wpk, b1, b2, out);
}

// Round 11
// 773.829 us; speedup vs baseline: 1.0014x; 1.0014x over previous
//
#include <hip/hip_runtime.h>

#define N_NODES 100000
#define N_EDGES 1600000
#define DIM 64

#define BIN_SHIFT 8
#define BIN_NODES 256
#define NBINS ((N_NODES + BIN_NODES - 1) / BIN_NODES)   // 391
#define GB_PAD 66                                        // acc row stride (words)

#define TILE_A 8192
#define EPB (TILE_A / 256)                               // 32 edges/thread
#define NBLK_A ((N_EDGES + TILE_A - 1) / TILE_A)         // 196

typedef __attribute__((ext_vector_type(8))) short bf16x8;
typedef __attribute__((ext_vector_type(4))) float f32x4;

// ---- bf16 helpers (hand-rolled, RNE; inputs are finite) --------------------
__device__ __forceinline__ float bflo(unsigned u) { return __uint_as_float(u << 16); }
__device__ __forceinline__ float bfhi(unsigned u) { return __uint_as_float(u & 0xFFFF0000u); }
__device__ __forceinline__ unsigned f2bf(float f) {
    unsigned u = __float_as_uint(f);
    u += 0x7FFFu + ((u >> 16) & 1u);
    return u >> 16;
}

// ---------------------------------------------------------------------------
// prep: rx = relu(x) as bf16, packed. 4 floats / thread.
// ---------------------------------------------------------------------------
__global__ __launch_bounds__(256) void prep_relu(
    const float* __restrict__ x, unsigned* __restrict__ rx)
{
    const int i = blockIdx.x * blockDim.x + threadIdx.x;
    if (i >= N_NODES * DIM / 4) return;
    const float4 v = reinterpret_cast<const float4*>(x)[i];
    uint2 o;
    o.x = f2bf(fmaxf(v.x, 0.f)) | (f2bf(fmaxf(v.y, 0.f)) << 16);
    o.y = f2bf(fmaxf(v.z, 0.f)) | (f2bf(fmaxf(v.w, 0.f)) << 16);
    reinterpret_cast<uint2*>(rx)[i] = o;
}

// ---------------------------------------------------------------------------
// wprep: prepack W1,W2 into MFMA B-frag lane order, bf16.
// ---------------------------------------------------------------------------
__global__ __launch_bounds__(256) void wprep(
    const float* __restrict__ W1, const float* __restrict__ W2,
    unsigned short* __restrict__ Wpk)
{
    const int idx = blockIdx.x * 256 + threadIdx.x;
    if (idx >= 8192) return;
    const int j    = idx & 7;
    const int lane = (idx >> 3) & 63;
    const int kk   = (idx >> 9) & 1;
    const int n    = (idx >> 10) & 3;
    const int L    = idx >> 12;
    const float* W = L ? W2 : W1;
    const int k    = kk * 32 + (lane >> 4) * 8 + j;
    const int col  = n * 16 + (lane & 15);
    Wpk[idx] = (unsigned short)f2bf(W[k * DIM + col]);
}

// ---------------------------------------------------------------------------
// bincount: coarse-bin histogram via LDS aggregation (391 bins of 256 nodes).
// ---------------------------------------------------------------------------
__global__ __launch_bounds__(256) void bincount(
    const int* __restrict__ ei, int* __restrict__ binc)
{
    __shared__ int lh[NBINS];
    for (int i = threadIdx.x; i < NBINS; i += 256) lh[i] = 0;
    __syncthreads();
    const int t = blockIdx.x * blockDim.x + threadIdx.x;
    const int e = t * 4;
    if (e + 3 < N_EDGES) {
        const int4 d4 = *reinterpret_cast<const int4*>(ei + N_EDGES + e);
        atomicAdd(&lh[d4.x >> BIN_SHIFT], 1);
        atomicAdd(&lh[d4.y >> BIN_SHIFT], 1);
        atomicAdd(&lh[d4.z >> BIN_SHIFT], 1);
        atomicAdd(&lh[d4.w >> BIN_SHIFT], 1);
    } else {
        for (int k = e; k < N_EDGES; ++k)
            atomicAdd(&lh[ei[N_EDGES + k] >> BIN_SHIFT], 1);
    }
    __syncthreads();
    for (int i = threadIdx.x; i < NBINS; i += 256)
        if (lh[i]) atomicAdd(&binc[i], lh[i]);
}

// ---------------------------------------------------------------------------
// binscan: single block, 2-per-thread exclusive scan of 391 bin counts
// -> binbase[392]; seeds gcur.
// ---------------------------------------------------------------------------
__global__ __launch_bounds__(256) void binscan(
    const int* __restrict__ binc, int* __restrict__ binbase,
    int* __restrict__ gcur)
{
    __shared__ int ls[256];
    const int t = threadIdx.x;
    const int a0 = (2 * t     < NBINS) ? binc[2 * t]     : 0;
    const int a1 = (2 * t + 1 < NBINS) ? binc[2 * t + 1] : 0;
    const int ps = a0 + a1;
    ls[t] = ps;
    __syncthreads();
    #pragma unroll
    for (int d = 1; d < 256; d <<= 1) {
        const int add = (t >= d) ? ls[t - d] : 0;
        __syncthreads();
        ls[t] += add;
        __syncthreads();
    }
    const int pb = ls[t] - ps;
    if (2 * t < NBINS)     { binbase[2 * t]     = pb;      gcur[2 * t]     = pb; }
    if (2 * t + 1 < NBINS) { binbase[2 * t + 1] = pb + a0; gcur[2 * t + 1] = pb + a0; }
    if (t == 0) binbase[NBINS] = N_EDGES;
}

// ---------------------------------------------------------------------------
// binscatter: block stages TILE_A=8192 edges in LDS grouped by bin (dst>>8),
// allocates one contiguous run per bin (global atomic on gcur), streams out
// packed entries (src<<8 | dst&255). Runs avg ~21 entries (84 B).
// ---------------------------------------------------------------------------
__global__ __launch_bounds__(256) void binscatter(
    const int* __restrict__ ei,
    int* __restrict__ gcur,
    unsigned* __restrict__ binned)
{
    __shared__ int lhist[NBINS];
    __shared__ int lbase[NBINS];
    __shared__ int lcur[NBINS];
    __shared__ int ldelta[NBINS];
    __shared__ int ls[256];
    __shared__ unsigned staged[TILE_A];
    __shared__ unsigned short sbin[TILE_A];

    const int t  = threadIdx.x;
    const int e0 = blockIdx.x * TILE_A;
    const int n  = min(TILE_A, N_EDGES - e0);

    for (int i = t; i < NBINS; i += 256) { lhist[i] = 0; lcur[i] = 0; }
    __syncthreads();

    int      mybin[EPB];
    unsigned myval[EPB];
    #pragma unroll
    for (int j = 0; j < EPB; ++j) {
        const int idx = t + j * 256;
        if (idx < n) {
            const int s = ei[e0 + idx];
            const int d = ei[N_EDGES + e0 + idx];
            mybin[j] = d >> BIN_SHIFT;
            myval[j] = ((unsigned)s << BIN_SHIFT) | (unsigned)(d & (BIN_NODES - 1));
            atomicAdd(&lhist[mybin[j]], 1);
        } else {
            mybin[j] = -1;
        }
    }
    __syncthreads();

    // 2-per-thread exclusive scan of lhist[0..390] -> lbase
    const int a0 = (2 * t     < NBINS) ? lhist[2 * t]     : 0;
    const int a1 = (2 * t + 1 < NBINS) ? lhist[2 * t + 1] : 0;
    const int ps = a0 + a1;
    ls[t] = ps;
    __syncthreads();
    #pragma unroll
    for (int d = 1; d < 256; d <<= 1) {
        const int add = (t >= d) ? ls[t - d] : 0;
        __syncthreads();
        ls[t] += add;
        __syncthreads();
    }
    const int pb = ls[t] - ps;
    if (2 * t < NBINS)     lbase[2 * t]     = pb;
    if (2 * t + 1 < NBINS) lbase[2 * t + 1] = pb + a0;
    __syncthreads();

    // allocate global runs
    for (int i = t; i < NBINS; i += 256) {
        const int c = lhist[i];
        ldelta[i] = (c > 0) ? (atomicAdd(&gcur[i], c) - lbase[i]) : 0;
    }
    __syncthreads();

    // stage into LDS grouped by bin
    #pragma unroll
    for (int j = 0; j < EPB; ++j) {
        if (mybin[j] >= 0) {
            const int p = lbase[mybin[j]] + atomicAdd(&lcur[mybin[j]], 1);
            staged[p] = myval[j];
            sbin[p]   = (unsigned short)mybin[j];
        }
    }
    __syncthreads();

    for (int p = t; p < n; p += 256)
        binned[p + ldelta[sbin[p]]] = staged[p];
}

// ---------------------------------------------------------------------------
// bin_gather: one block per 256-node bin. LDS f32 accumulators (row stride 66
// words). Each wave: 64-entry coalesced chunk, 8-lane subgroup per edge,
// 8 rx-rows (128 B each) in flight, NATIVE ds_add_f32 accumulate
// (atomicAdd on the __shared__ array expression — NOT a generic pointer,
// NOT unsafeAtomicAdd, which takes the flat/global path for LDS addresses).
// Epilogue: h = x + acc -> hbuf (bf16 pairs).
// ---------------------------------------------------------------------------
__global__ __launch_bounds__(512) void bin_gather(
    const float*  __restrict__ x,
    const unsigned char* __restrict__ rx,     // bf16 rows, 128 B each
    const unsigned* __restrict__ binned,
    const int* __restrict__ binbase,
    unsigned* __restrict__ hbuf)
{
    __shared__ float acc[BIN_NODES * GB_PAD];  // 256*66*4 = 67584 B

    const int b     = blockIdx.x;
    const int node0 = b << BIN_SHIFT;
    const int nloc  = min(BIN_NODES, N_NODES - node0);
    const int base  = binbase[b];
    const int cnt   = binbase[b + 1] - base;
    const int t     = threadIdx.x;
    const int lane  = t & 63;

    for (int i = t; i < BIN_NODES * GB_PAD; i += 512) acc[i] = 0.f;
    __syncthreads();

    const int sg = lane >> 3;        // edge subgroup 0..7
    const int c  = lane & 7;         // 16B chunk of the 128B row

    for (int pb = (t >> 6) * 64; pb < cnt; pb += 512) {
        const int nv = min(64, cnt - pb);
        const unsigned my = (lane < nv) ? binned[base + pb + lane] : 0u;

        uint4 buf[8];
        unsigned ent[8];
        #pragma unroll
        for (int k = 0; k < 8; ++k) {
            const int ep = k * 8 + sg;
            ent[k] = (unsigned)__shfl((int)my, ep, 64);
            if (ep < nv) {
                const unsigned src = ent[k] >> BIN_SHIFT;
                buf[k] = *reinterpret_cast<const uint4*>(
                    rx + (size_t)src * 128 + c * 16);
            }
        }
        #pragma unroll
        for (int k = 0; k < 8; ++k) {
            const int ep = k * 8 + sg;
            if (ep < nv) {
                const int dstl = (int)(ent[k] & (BIN_NODES - 1));
                const int ai = dstl * GB_PAD + c * 8;
                atomicAdd(&acc[ai + 0], bflo(buf[k].x));
                atomicAdd(&acc[ai + 1], bfhi(buf[k].x));
                atomicAdd(&acc[ai + 2], bflo(buf[k].y));
                atomicAdd(&acc[ai + 3], bfhi(buf[k].y));
                atomicAdd(&acc[ai + 4], bflo(buf[k].z));
                atomicAdd(&acc[ai + 5], bfhi(buf[k].z));
                atomicAdd(&acc[ai + 6], bflo(buf[k].w));
                atomicAdd(&acc[ai + 7], bfhi(buf[k].w));
            }
        }
    }
    __syncthreads();

    // h = x + acc, packed bf16 pairs, coalesced
    for (int i = t; i < nloc * 32; i += 512) {
        const int nl = i >> 5;
        const int dp = i & 31;
        const float2 xv = *reinterpret_cast<const float2*>(
            x + (size_t)(node0 + nl) * DIM + dp * 2);
        const float2 av = *reinterpret_cast<const float2*>(
            &acc[nl * GB_PAD + dp * 2]);
        const float h0 = xv.x + av.x;
        const float h1 = xv.y + av.y;
        hbuf[(size_t)(node0 + nl) * 32 + dp] = f2bf(h0) | (f2bf(h1) << 16);
    }
}

// ---------------------------------------------------------------------------
// mlp_mfma: per wave, 16 nodes; two MFMA GEMMs, fused bias+relu (unchanged).
// ---------------------------------------------------------------------------
__global__ __launch_bounds__(256) void mlp_mfma(
    const unsigned* __restrict__ hbuf,       // bf16 rows, 128 B each
    const unsigned short* __restrict__ Wpk,  // prepacked B-frags
    const float* __restrict__ b1,
    const float* __restrict__ b2,
    float* __restrict__ out)
{
    __shared__ float yt[4][16 * 68];

    const int wiv  = threadIdx.x >> 6;
    const int lane = threadIdx.x & 63;
    const int wid  = blockIdx.x * 4 + wiv;
    const int r0   = wid * 16;
    if (r0 >= N_NODES) return;

    const int lrow = lane & 15;
    const int lgrp = lane >> 4;

    const int hrow = min(r0 + lrow, N_NODES - 1);
    const uint4* hrowp =
        reinterpret_cast<const uint4*>((const char*)hbuf + (size_t)hrow * 128);
    union UF { uint4 u; bf16x8 v; };
    UF ha0, ha1;
    ha0.u = hrowp[lgrp];
    ha1.u = hrowp[lgrp + 4];

    const uint4* wp = reinterpret_cast<const uint4*>(Wpk);

    float* my = &yt[wiv][0];
    #pragma unroll
    for (int n = 0; n < 4; ++n) {
        const float bi = b1[n * 16 + lrow];
        f32x4 acc = {bi, bi, bi, bi};
        UF bw0, bw1;
        bw0.u = wp[(n * 2 + 0) * 64 + lane];
        bw1.u = wp[(n * 2 + 1) * 64 + lane];
        acc = __builtin_amdgcn_mfma_f32_16x16x32_bf16(ha0.v, bw0.v, acc, 0, 0, 0);
        acc = __builtin_amdgcn_mfma_f32_16x16x32_bf16(ha1.v, bw1.v, acc, 0, 0, 0);
        #pragma unroll
        for (int i = 0; i < 4; ++i)
            my[(lgrp * 4 + i) * 68 + n * 16 + lrow] = fmaxf(acc[i], 0.f);
    }

    const float* yr = &yt[wiv][lrow * 68 + lgrp * 8];
    const float4 p0 = *reinterpret_cast<const float4*>(yr + 0);
    const float4 p1 = *reinterpret_cast<const float4*>(yr + 4);
    const float4 p2 = *reinterpret_cast<const float4*>(yr + 32);
    const float4 p3 = *reinterpret_cast<const float4*>(yr + 36);

    union UB { bf16x8 v; unsigned short s[8]; };
    UB ya0, ya1;
    ya0.s[0] = (unsigned short)f2bf(p0.x); ya0.s[1] = (unsigned short)f2bf(p0.y);
    ya0.s[2] = (unsigned short)f2bf(p0.z); ya0.s[3] = (unsigned short)f2bf(p0.w);
    ya0.s[4] = (unsigned short)f2bf(p1.x); ya0.s[5] = (unsigned short)f2bf(p1.y);
    ya0.s[6] = (unsigned short)f2bf(p1.z); ya0.s[7] = (unsigned short)f2bf(p1.w);
    ya1.s[0] = (unsigned short)f2bf(p2.x); ya1.s[1] = (unsigned short)f2bf(p2.y);
    ya1.s[2] = (unsigned short)f2bf(p2.z); ya1.s[3] = (unsigned short)f2bf(p2.w);
    ya1.s[4] = (unsigned short)f2bf(p3.x); ya1.s[5] = (unsigned short)f2bf(p3.y);
    ya1.s[6] = (unsigned short)f2bf(p3.z); ya1.s[7] = (unsigned short)f2bf(p3.w);

    #pragma unroll
    for (int n = 0; n < 4; ++n) {
        const float bi = b2[n * 16 + lrow];
        f32x4 acc = {bi, bi, bi, bi};
        UF bw0, bw1;
        bw0.u = wp[(8 + n * 2 + 0) * 64 + lane];
        bw1.u = wp[(8 + n * 2 + 1) * 64 + lane];
        acc = __builtin_amdgcn_mfma_f32_16x16x32_bf16(ya0.v, bw0.v, acc, 0, 0, 0);
        acc = __builtin_amdgcn_mfma_f32_16x16x32_bf16(ya1.v, bw1.v, acc, 0, 0, 0);
        #pragma unroll
        for (int i = 0; i < 4; ++i) {
            const int r = r0 + lgrp * 4 + i;
            if (r < N_NODES)
                out[(size_t)r * DIM + n * 16 + lrow] = fmaxf(acc[i], 0.f);
        }
    }
}

// ---------------------------------------------------------------------------
extern "C" void kernel_launch(void* const* d_in, const int* in_sizes, int n_in,
                              void* d_out, int out_size, void* d_ws, size_t ws_size,
                              hipStream_t stream) {
    const float* x  = (const float*)d_in[0];
    const int*   ei = (const int*)d_in[1];
    const float* W1 = (const float*)d_in[2];
    const float* b1 = (const float*)d_in[3];
    const float* W2 = (const float*)d_in[4];
    const float* b2 = (const float*)d_in[5];
    float* out = (float*)d_out;

    // rx (relu(x) in bf16, 12.8 MB) lives in d_out; fully consumed by
    // bin_gather before mlp_mfma overwrites d_out.
    unsigned* rx = (unsigned*)d_out;

    // workspace: binc | binbase | gcur | binned | hbuf | Wpk  (~19.2 MB)
    int* binc    = (int*)d_ws;                 // 391 (pad 512)
    int* binbase = binc + 512;                 // 392 (pad 512)
    int* gcur    = binbase + 512;              // 391 (pad 512)
    unsigned* binned = (unsigned*)(gcur + 512);          // N_EDGES
    unsigned* hbuf   = binned + N_EDGES;                 // N_NODES*32 uints
    unsigned short* Wpk =
        (unsigned short*)(hbuf + (size_t)N_NODES * 32);  // 8192 bf16

    hipMemsetAsync(binc, 0, NBINS * sizeof(int), stream);

    prep_relu<<<(N_NODES * DIM / 4 + 255) / 256, 256, 0, stream>>>(x, rx);
    wprep<<<32, 256, 0, stream>>>(W1, W2, Wpk);

    const int eblocks4 = (N_EDGES / 4 + 255) / 256;
    bincount<<<eblocks4, 256, 0, stream>>>(ei, binc);
    binscan<<<1, 256, 0, stream>>>(binc, binbase, gcur);
    binscatter<<<NBLK_A, 256, 0, stream>>>(ei, gcur, binned);

    bin_gather<<<NBINS, 512, 0, stream>>>(
        x, (const unsigned char*)rx, binned, binbase, hbuf);

    mlp_mfma<<<(N_NODES + 63) / 64, 256, 0, stream>>>(
        hbuf, Wpk, b1, b2, out);
}

// Round 12
// 132.501 us; speedup vs baseline: 5.8482x; 5.8402x over previous
//
#include <hip/hip_runtime.h>

#define N_NODES 100000
#define N_EDGES 1600000
#define DIM 64

#define BIN_SHIFT 9
#define BIN_NODES 512
#define NBINS ((N_NODES + BIN_NODES - 1) / BIN_NODES)   // 196
#define TILE_A 4096
#define NBLK_A ((N_EDGES + TILE_A - 1) / TILE_A)        // 391
#define CAP_B 9216          // mean 8192 + ~11 sigma

typedef __attribute__((ext_vector_type(8))) short bf16x8;
typedef __attribute__((ext_vector_type(4))) float f32x4;

// ---- bf16 helpers (hand-rolled, RNE; inputs are finite) --------------------
__device__ __forceinline__ float bflo(unsigned u) { return __uint_as_float(u << 16); }
__device__ __forceinline__ float bfhi(unsigned u) { return __uint_as_float(u & 0xFFFF0000u); }
__device__ __forceinline__ unsigned f2bf(float f) {
    unsigned u = __float_as_uint(f);
    u += 0x7FFFu + ((u >> 16) & 1u);
    return u >> 16;
}

// ---------------------------------------------------------------------------
// prep: rx = relu(x) as bf16, packed. 4 floats / thread.
// ---------------------------------------------------------------------------
__global__ __launch_bounds__(256) void prep_relu(
    const float* __restrict__ x, unsigned* __restrict__ rx)
{
    const int i = blockIdx.x * blockDim.x + threadIdx.x;
    if (i >= N_NODES * DIM / 4) return;
    const float4 v = reinterpret_cast<const float4*>(x)[i];
    uint2 o;
    o.x = f2bf(fmaxf(v.x, 0.f)) | (f2bf(fmaxf(v.y, 0.f)) << 16);
    o.y = f2bf(fmaxf(v.z, 0.f)) | (f2bf(fmaxf(v.w, 0.f)) << 16);
    reinterpret_cast<uint2*>(rx)[i] = o;
}

// ---------------------------------------------------------------------------
// wprep: prepack W1,W2 into MFMA B-frag lane order, bf16.
// ---------------------------------------------------------------------------
__global__ __launch_bounds__(256) void wprep(
    const float* __restrict__ W1, const float* __restrict__ W2,
    unsigned short* __restrict__ Wpk)
{
    const int idx = blockIdx.x * 256 + threadIdx.x;
    if (idx >= 8192) return;
    const int j    = idx & 7;
    const int lane = (idx >> 3) & 63;
    const int kk   = (idx >> 9) & 1;
    const int n    = (idx >> 10) & 3;
    const int L    = idx >> 12;
    const float* W = L ? W2 : W1;
    const int k    = kk * 32 + (lane >> 4) * 8 + j;
    const int col  = n * 16 + (lane & 15);
    Wpk[idx] = (unsigned short)f2bf(W[k * DIM + col]);
}

// ---------------------------------------------------------------------------
// bincount: coarse-bin histogram via LDS aggregation (196 bins of 512 nodes).
// ---------------------------------------------------------------------------
__global__ __launch_bounds__(256) void bincount(
    const int* __restrict__ ei, int* __restrict__ binc)
{
    __shared__ int lh[NBINS];
    for (int i = threadIdx.x; i < NBINS; i += 256) lh[i] = 0;
    __syncthreads();
    const int t = blockIdx.x * blockDim.x + threadIdx.x;
    const int e = t * 4;
    if (e + 3 < N_EDGES) {
        const int4 d4 = *reinterpret_cast<const int4*>(ei + N_EDGES + e);
        atomicAdd(&lh[d4.x >> BIN_SHIFT], 1);
        atomicAdd(&lh[d4.y >> BIN_SHIFT], 1);
        atomicAdd(&lh[d4.z >> BIN_SHIFT], 1);
        atomicAdd(&lh[d4.w >> BIN_SHIFT], 1);
    } else {
        for (int k = e; k < N_EDGES; ++k)
            atomicAdd(&lh[ei[N_EDGES + k] >> BIN_SHIFT], 1);
    }
    __syncthreads();
    for (int i = threadIdx.x; i < NBINS; i += 256)
        if (lh[i]) atomicAdd(&binc[i], lh[i]);
}

// ---------------------------------------------------------------------------
// binscan: single block scans the 196 bin counts -> binbase; seeds gcur.
// ---------------------------------------------------------------------------
__global__ __launch_bounds__(256) void binscan(
    const int* __restrict__ binc, int* __restrict__ binbase,
    int* __restrict__ gcur)
{
    __shared__ int s[256];
    const int t = threadIdx.x;
    const int v = (t < NBINS) ? binc[t] : 0;
    s[t] = v;
    __syncthreads();
    #pragma unroll
    for (int d = 1; d < 256; d <<= 1) {
        const int add = (t >= d) ? s[t - d] : 0;
        __syncthreads();
        s[t] += add;
        __syncthreads();
    }
    if (t < NBINS) {
        const int base = s[t] - v;
        binbase[t] = base;
        gcur[t]    = base;
    }
    if (t == 0) binbase[NBINS] = N_EDGES;
}

// ---------------------------------------------------------------------------
// Pass A: binscatter. Block stages TILE_A edges in LDS grouped by coarse bin
// (dst>>9), allocates one contiguous run per bin via global atomic, streams
// out packed entries (src<<9 | dst&511).
// ---------------------------------------------------------------------------
__global__ __launch_bounds__(256) void binscatter(
    const int* __restrict__ ei,
    int* __restrict__ gcur,
    unsigned* __restrict__ binned)
{
    __shared__ int lhist[NBINS];
    __shared__ int lbase[NBINS];
    __shared__ int lcur[NBINS];
    __shared__ int ldelta[NBINS];
    __shared__ int ls[256];
    __shared__ unsigned staged[TILE_A];
    __shared__ unsigned char sbin[TILE_A];

    const int t  = threadIdx.x;
    const int e0 = blockIdx.x * TILE_A;
    const int n  = min(TILE_A, N_EDGES - e0);

    for (int i = t; i < NBINS; i += 256) { lhist[i] = 0; lcur[i] = 0; }
    __syncthreads();

    int      mybin[TILE_A / 256];
    unsigned myval[TILE_A / 256];
    #pragma unroll
    for (int j = 0; j < TILE_A / 256; ++j) {
        const int idx = t + j * 256;
        if (idx < n) {
            const int s = ei[e0 + idx];
            const int d = ei[N_EDGES + e0 + idx];
            mybin[j] = d >> BIN_SHIFT;
            myval[j] = ((unsigned)s << BIN_SHIFT) | (unsigned)(d & (BIN_NODES - 1));
            atomicAdd(&lhist[mybin[j]], 1);
        } else {
            mybin[j] = -1;
        }
    }
    __syncthreads();

    ls[t] = (t < NBINS) ? lhist[t] : 0;
    __syncthreads();
    #pragma unroll
    for (int d = 1; d < 256; d <<= 1) {
        const int add = (t >= d) ? ls[t - d] : 0;
        __syncthreads();
        ls[t] += add;
        __syncthreads();
    }
    if (t < NBINS) lbase[t] = ls[t] - lhist[t];
    __syncthreads();

    if (t < NBINS) {
        const int c = lhist[t];
        ldelta[t] = (c > 0) ? (atomicAdd(&gcur[t], c) - lbase[t]) : 0;
    }
    __syncthreads();

    #pragma unroll
    for (int j = 0; j < TILE_A / 256; ++j) {
        if (mybin[j] >= 0) {
            const int p = lbase[mybin[j]] + atomicAdd(&lcur[mybin[j]], 1);
            staged[p] = myval[j];
            sbin[p]   = (unsigned char)mybin[j];
        }
    }
    __syncthreads();

    for (int p = t; p < n; p += 256)
        binned[p + ldelta[sbin[p]]] = staged[p];
}

// ---------------------------------------------------------------------------
// Pass B: binsort. One block per bin: per-node degrees in LDS, writes the
// off[] segment, LDS-sorts entries into final CSR order, streams out.
// ---------------------------------------------------------------------------
__global__ __launch_bounds__(256) void binsort(
    const unsigned* __restrict__ binned,
    const int* __restrict__ binbase,
    int* __restrict__ off,
    int* __restrict__ slot)
{
    __shared__ int lhist[BIN_NODES];
    __shared__ int lofs[BIN_NODES];
    __shared__ int lcur[BIN_NODES];
    __shared__ int ls[256];
    __shared__ int sseg[CAP_B];

    const int b     = blockIdx.x;
    const int node0 = b << BIN_SHIFT;
    const int nloc  = min(BIN_NODES, N_NODES - node0);
    const int rbase = binbase[b];
    const int cnt   = binbase[b + 1] - rbase;
    const int t     = threadIdx.x;

    for (int i = t; i < BIN_NODES; i += 256) { lhist[i] = 0; lcur[i] = 0; }
    __syncthreads();

    for (int p = t; p < cnt; p += 256)
        atomicAdd(&lhist[binned[rbase + p] & (BIN_NODES - 1)], 1);
    __syncthreads();

    const int a0 = lhist[2 * t];
    const int a1 = lhist[2 * t + 1];
    const int ps = a0 + a1;
    ls[t] = ps;
    __syncthreads();
    #pragma unroll
    for (int d = 1; d < 256; d <<= 1) {
        const int add = (t >= d) ? ls[t - d] : 0;
        __syncthreads();
        ls[t] += add;
        __syncthreads();
    }
    const int pbase = ls[t] - ps;
    lofs[2 * t]     = pbase;
    lofs[2 * t + 1] = pbase + a0;
    __syncthreads();

    for (int i = t; i < nloc; i += 256)
        off[node0 + i] = rbase + lofs[i];
    if (b == NBINS - 1 && t == 0) off[N_NODES] = N_EDGES;

    if (cnt <= CAP_B) {
        for (int p = t; p < cnt; p += 256) {
            const unsigned v = binned[rbase + p];
            const int dl  = v & (BIN_NODES - 1);
            const int rel = lofs[dl] + atomicAdd(&lcur[dl], 1);
            sseg[rel] = (int)(v >> BIN_SHIFT);
        }
        __syncthreads();
        for (int p = t; p < cnt; p += 256)
            slot[rbase + p] = sseg[p];
    } else {
        for (int p = t; p < cnt; p += 256) {
            const unsigned v = binned[rbase + p];
            const int dl  = v & (BIN_NODES - 1);
            const int rel = lofs[dl] + atomicAdd(&lcur[dl], 1);
            slot[rbase + rel] = (int)(v >> BIN_SHIFT);
        }
    }
}

// ---------------------------------------------------------------------------
// gather8: 8 nodes per wave, 8 lanes per node (g = lane>>3 node subgroup,
// c = lane&7 dim-chunk). Each lane exclusively owns dims c*8..c*8+7 of its
// node -> NO cross-lane reduce, no select tree. Per 8-edge chunk: 1 coalesced
// slot load + 8 in-group broadcasts + 8 row loads ALL IN FLIGHT (64 lines in
// flight per wave, degree-independent). Epilogue: h = x + acc -> one uint4
// store per lane (coalesced 128 B per node).
// ---------------------------------------------------------------------------
__global__ __launch_bounds__(256) void gather8(
    const float* __restrict__ x,
    const unsigned char* __restrict__ rx,    // bf16 rows, 128 B each
    const int*   __restrict__ off,
    const int*   __restrict__ slot,
    unsigned*    __restrict__ hbuf)
{
    const int wave = (blockIdx.x * blockDim.x + threadIdx.x) >> 6;
    const int lane = threadIdx.x & 63;
    const int g    = lane >> 3;
    const int c    = lane & 7;
    const int node = wave * 8 + g;          // N_NODES % 8 == 0: always valid

    const int beg = off[node];
    const int end = off[node + 1];

    float acc[8];
    #pragma unroll
    for (int e = 0; e < 8; ++e) acc[e] = 0.f;

    for (int kb = beg; kb < end; kb += 8) {
        // lane c of group g holds slot[kb_g + c]
        const int sv = (kb + c < end) ? slot[kb + c] : 0;

        int srcs[8];
        #pragma unroll
        for (int j = 0; j < 8; ++j) {
            const int s = __shfl(sv, g * 8 + j, 64);
            srcs[j] = (kb + j < end) ? s : 0;   // clamp: dummy row-0 load
        }
        uint4 buf[8];
        #pragma unroll
        for (int j = 0; j < 8; ++j)
            buf[j] = *reinterpret_cast<const uint4*>(
                rx + (size_t)srcs[j] * 128 + c * 16);
        #pragma unroll
        for (int j = 0; j < 8; ++j) {
            if (kb + j < end) {
                acc[0] += bflo(buf[j].x); acc[1] += bfhi(buf[j].x);
                acc[2] += bflo(buf[j].y); acc[3] += bfhi(buf[j].y);
                acc[4] += bflo(buf[j].z); acc[5] += bfhi(buf[j].z);
                acc[6] += bflo(buf[j].w); acc[7] += bfhi(buf[j].w);
            }
        }
    }

    // epilogue: h = x + acc for dims c*8..c*8+7, pack bf16 pairs, uint4 store
    const float4 x0 = *reinterpret_cast<const float4*>(
        x + (size_t)node * DIM + c * 8);
    const float4 x1 = *reinterpret_cast<const float4*>(
        x + (size_t)node * DIM + c * 8 + 4);
    uint4 o;
    o.x = f2bf(x0.x + acc[0]) | (f2bf(x0.y + acc[1]) << 16);
    o.y = f2bf(x0.z + acc[2]) | (f2bf(x0.w + acc[3]) << 16);
    o.z = f2bf(x1.x + acc[4]) | (f2bf(x1.y + acc[5]) << 16);
    o.w = f2bf(x1.z + acc[6]) | (f2bf(x1.w + acc[7]) << 16);
    reinterpret_cast<uint4*>(hbuf)[(size_t)node * 8 + c] = o;
}

// ---------------------------------------------------------------------------
// mlp_mfma: per wave, 16 nodes; two MFMA GEMMs, fused bias+relu (unchanged).
// ---------------------------------------------------------------------------
__global__ __launch_bounds__(256) void mlp_mfma(
    const unsigned* __restrict__ hbuf,       // bf16 rows, 128 B each
    const unsigned short* __restrict__ Wpk,  // prepacked B-frags
    const float* __restrict__ b1,
    const float* __restrict__ b2,
    float* __restrict__ out)
{
    __shared__ float yt[4][16 * 68];

    const int wiv  = threadIdx.x >> 6;
    const int lane = threadIdx.x & 63;
    const int wid  = blockIdx.x * 4 + wiv;
    const int r0   = wid * 16;
    if (r0 >= N_NODES) return;

    const int lrow = lane & 15;
    const int lgrp = lane >> 4;

    const int hrow = min(r0 + lrow, N_NODES - 1);
    const uint4* hrowp =
        reinterpret_cast<const uint4*>((const char*)hbuf + (size_t)hrow * 128);
    union UF { uint4 u; bf16x8 v; };
    UF ha0, ha1;
    ha0.u = hrowp[lgrp];
    ha1.u = hrowp[lgrp + 4];

    const uint4* wp = reinterpret_cast<const uint4*>(Wpk);

    float* my = &yt[wiv][0];
    #pragma unroll
    for (int n = 0; n < 4; ++n) {
        const float bi = b1[n * 16 + lrow];
        f32x4 acc = {bi, bi, bi, bi};
        UF bw0, bw1;
        bw0.u = wp[(n * 2 + 0) * 64 + lane];
        bw1.u = wp[(n * 2 + 1) * 64 + lane];
        acc = __builtin_amdgcn_mfma_f32_16x16x32_bf16(ha0.v, bw0.v, acc, 0, 0, 0);
        acc = __builtin_amdgcn_mfma_f32_16x16x32_bf16(ha1.v, bw1.v, acc, 0, 0, 0);
        #pragma unroll
        for (int i = 0; i < 4; ++i)
            my[(lgrp * 4 + i) * 68 + n * 16 + lrow] = fmaxf(acc[i], 0.f);
    }

    const float* yr = &yt[wiv][lrow * 68 + lgrp * 8];
    const float4 p0 = *reinterpret_cast<const float4*>(yr + 0);
    const float4 p1 = *reinterpret_cast<const float4*>(yr + 4);
    const float4 p2 = *reinterpret_cast<const float4*>(yr + 32);
    const float4 p3 = *reinterpret_cast<const float4*>(yr + 36);

    union UB { bf16x8 v; unsigned short s[8]; };
    UB ya0, ya1;
    ya0.s[0] = (unsigned short)f2bf(p0.x); ya0.s[1] = (unsigned short)f2bf(p0.y);
    ya0.s[2] = (unsigned short)f2bf(p0.z); ya0.s[3] = (unsigned short)f2bf(p0.w);
    ya0.s[4] = (unsigned short)f2bf(p1.x); ya0.s[5] = (unsigned short)f2bf(p1.y);
    ya0.s[6] = (unsigned short)f2bf(p1.z); ya0.s[7] = (unsigned short)f2bf(p1.w);
    ya1.s[0] = (unsigned short)f2bf(p2.x); ya1.s[1] = (unsigned short)f2bf(p2.y);
    ya1.s[2] = (unsigned short)f2bf(p2.z); ya1.s[3] = (unsigned short)f2bf(p2.w);
    ya1.s[4] = (unsigned short)f2bf(p3.x); ya1.s[5] = (unsigned short)f2bf(p3.y);
    ya1.s[6] = (unsigned short)f2bf(p3.z); ya1.s[7] = (unsigned short)f2bf(p3.w);

    #pragma unroll
    for (int n = 0; n < 4; ++n) {
        const float bi = b2[n * 16 + lrow];
        f32x4 acc = {bi, bi, bi, bi};
        UF bw0, bw1;
        bw0.u = wp[(8 + n * 2 + 0) * 64 + lane];
        bw1.u = wp[(8 + n * 2 + 1) * 64 + lane];
        acc = __builtin_amdgcn_mfma_f32_16x16x32_bf16(ya0.v, bw0.v, acc, 0, 0, 0);
        acc = __builtin_amdgcn_mfma_f32_16x16x32_bf16(ya1.v, bw1.v, acc, 0, 0, 0);
        #pragma unroll
        for (int i = 0; i < 4; ++i) {
            const int r = r0 + lgrp * 4 + i;
            if (r < N_NODES)
                out[(size_t)r * DIM + n * 16 + lrow] = fmaxf(acc[i], 0.f);
        }
    }
}

// ---------------------------------------------------------------------------
extern "C" void kernel_launch(void* const* d_in, const int* in_sizes, int n_in,
                              void* d_out, int out_size, void* d_ws, size_t ws_size,
                              hipStream_t stream) {
    const float* x  = (const float*)d_in[0];
    const int*   ei = (const int*)d_in[1];
    const float* W1 = (const float*)d_in[2];
    const float* b1 = (const float*)d_in[3];
    const float* W2 = (const float*)d_in[4];
    const float* b2 = (const float*)d_in[5];
    float* out = (float*)d_out;

    // rx (relu(x) in bf16, 12.8 MB) lives in d_out; fully consumed by gather8
    // before mlp_mfma overwrites d_out.
    unsigned* rx = (unsigned*)d_out;

    // workspace (ints): off | binc | binbase | gcur | slot | hbuf | Wpk
    // binned aliases hbuf (binned dead before gather8 writes hbuf).
    int* off     = (int*)d_ws;         // N_NODES + 1 (padded to 100352)
    int* binc    = off + 100352;       // 256
    int* binbase = binc + 256;         // NBINS + 1 (padded to 256)
    int* gcur    = binbase + 256;      // 256
    int* slot    = gcur + 256;         // N_EDGES
    unsigned* hbuf   = (unsigned*)(slot + N_EDGES);   // N_NODES*DIM bf16
    unsigned* binned = hbuf;                          // N_EDGES uints (alias)
    unsigned short* Wpk =
        (unsigned short*)(hbuf + (size_t)N_NODES * 32);  // 8192 bf16

    hipMemsetAsync(binc, 0, NBINS * sizeof(int), stream);

    prep_relu<<<(N_NODES * DIM / 4 + 255) / 256, 256, 0, stream>>>(x, rx);
    wprep<<<32, 256, 0, stream>>>(W1, W2, Wpk);

    const int eblocks4 = (N_EDGES / 4 + 255) / 256;
    bincount<<<eblocks4, 256, 0, stream>>>(ei, binc);
    binscan<<<1, 256, 0, stream>>>(binc, binbase, gcur);
    binscatter<<<NBLK_A, 256, 0, stream>>>(ei, gcur, binned);
    binsort<<<NBINS, 256, 0, stream>>>(binned, binbase, off, slot);

    // 8 nodes/wave, 4 waves/block -> 32 nodes/block; 100000/32 = 3125 exact
    gather8<<<3125, 256, 0, stream>>>(
        x, (const unsigned char*)rx, off, slot, hbuf);

    mlp_mfma<<<(N_NODES + 63) / 64, 256, 0, stream>>>(
        hbuf, Wpk, b1, b2, out);
}

// Round 13
// 126.086 us; speedup vs baseline: 6.1457x; 1.0509x over previous
//
#include <hip/hip_runtime.h>

#define N_NODES 100000
#define N_EDGES 1600000
#define DIM 64

#define BIN_SHIFT 9
#define BIN_NODES 512
#define NBINS ((N_NODES + BIN_NODES - 1) / BIN_NODES)   // 196
#define TILE_A 4096
#define NBLK_A ((N_EDGES + TILE_A - 1) / TILE_A)        // 391
#define CAP_B 9216          // mean 8192 + ~11 sigma

typedef __attribute__((ext_vector_type(8))) short bf16x8;
typedef __attribute__((ext_vector_type(4))) float f32x4;

// ---- bf16 helpers (hand-rolled, RNE; inputs are finite) --------------------
__device__ __forceinline__ float bflo(unsigned u) { return __uint_as_float(u << 16); }
__device__ __forceinline__ float bfhi(unsigned u) { return __uint_as_float(u & 0xFFFF0000u); }
__device__ __forceinline__ unsigned f2bf(float f) {
    unsigned u = __float_as_uint(f);
    u += 0x7FFFu + ((u >> 16) & 1u);
    return u >> 16;
}

// ---------------------------------------------------------------------------
// prep: rx = relu(x) as bf16, packed. 4 floats / thread.
// Block 0 also zeroes binc (replaces a 40 µs runtime fillBuffer dispatch!).
// ---------------------------------------------------------------------------
__global__ __launch_bounds__(256) void prep_relu(
    const float* __restrict__ x, unsigned* __restrict__ rx,
    int* __restrict__ binc)
{
    if (blockIdx.x == 0 && threadIdx.x < NBINS) binc[threadIdx.x] = 0;
    const int i = blockIdx.x * blockDim.x + threadIdx.x;
    if (i >= N_NODES * DIM / 4) return;
    const float4 v = reinterpret_cast<const float4*>(x)[i];
    uint2 o;
    o.x = f2bf(fmaxf(v.x, 0.f)) | (f2bf(fmaxf(v.y, 0.f)) << 16);
    o.y = f2bf(fmaxf(v.z, 0.f)) | (f2bf(fmaxf(v.w, 0.f)) << 16);
    reinterpret_cast<uint2*>(rx)[i] = o;
}

// ---------------------------------------------------------------------------
// wprep: prepack W1,W2 into MFMA B-frag lane order, bf16.
// ---------------------------------------------------------------------------
__global__ __launch_bounds__(256) void wprep(
    const float* __restrict__ W1, const float* __restrict__ W2,
    unsigned short* __restrict__ Wpk)
{
    const int idx = blockIdx.x * 256 + threadIdx.x;
    if (idx >= 8192) return;
    const int j    = idx & 7;
    const int lane = (idx >> 3) & 63;
    const int kk   = (idx >> 9) & 1;
    const int n    = (idx >> 10) & 3;
    const int L    = idx >> 12;
    const float* W = L ? W2 : W1;
    const int k    = kk * 32 + (lane >> 4) * 8 + j;
    const int col  = n * 16 + (lane & 15);
    Wpk[idx] = (unsigned short)f2bf(W[k * DIM + col]);
}

// ---------------------------------------------------------------------------
// bincount: coarse-bin histogram via LDS aggregation (196 bins of 512 nodes).
// ---------------------------------------------------------------------------
__global__ __launch_bounds__(256) void bincount(
    const int* __restrict__ ei, int* __restrict__ binc)
{
    __shared__ int lh[NBINS];
    for (int i = threadIdx.x; i < NBINS; i += 256) lh[i] = 0;
    __syncthreads();
    const int t = blockIdx.x * blockDim.x + threadIdx.x;
    const int e = t * 4;
    if (e + 3 < N_EDGES) {
        const int4 d4 = *reinterpret_cast<const int4*>(ei + N_EDGES + e);
        atomicAdd(&lh[d4.x >> BIN_SHIFT], 1);
        atomicAdd(&lh[d4.y >> BIN_SHIFT], 1);
        atomicAdd(&lh[d4.z >> BIN_SHIFT], 1);
        atomicAdd(&lh[d4.w >> BIN_SHIFT], 1);
    } else {
        for (int k = e; k < N_EDGES; ++k)
            atomicAdd(&lh[ei[N_EDGES + k] >> BIN_SHIFT], 1);
    }
    __syncthreads();
    for (int i = threadIdx.x; i < NBINS; i += 256)
        if (lh[i]) atomicAdd(&binc[i], lh[i]);
}

// ---------------------------------------------------------------------------
// binscan: single block scans the 196 bin counts -> binbase; seeds gcur.
// ---------------------------------------------------------------------------
__global__ __launch_bounds__(256) void binscan(
    const int* __restrict__ binc, int* __restrict__ binbase,
    int* __restrict__ gcur)
{
    __shared__ int s[256];
    const int t = threadIdx.x;
    const int v = (t < NBINS) ? binc[t] : 0;
    s[t] = v;
    __syncthreads();
    #pragma unroll
    for (int d = 1; d < 256; d <<= 1) {
        const int add = (t >= d) ? s[t - d] : 0;
        __syncthreads();
        s[t] += add;
        __syncthreads();
    }
    if (t < NBINS) {
        const int base = s[t] - v;
        binbase[t] = base;
        gcur[t]    = base;
    }
    if (t == 0) binbase[NBINS] = N_EDGES;
}

// ---------------------------------------------------------------------------
// Pass A: binscatter. Block stages TILE_A edges in LDS grouped by coarse bin
// (dst>>9), allocates one contiguous run per bin via global atomic, streams
// out packed entries (src<<9 | dst&511).
// ---------------------------------------------------------------------------
__global__ __launch_bounds__(256) void binscatter(
    const int* __restrict__ ei,
    int* __restrict__ gcur,
    unsigned* __restrict__ binned)
{
    __shared__ int lhist[NBINS];
    __shared__ int lbase[NBINS];
    __shared__ int lcur[NBINS];
    __shared__ int ldelta[NBINS];
    __shared__ int ls[256];
    __shared__ unsigned staged[TILE_A];
    __shared__ unsigned char sbin[TILE_A];

    const int t  = threadIdx.x;
    const int e0 = blockIdx.x * TILE_A;
    const int n  = min(TILE_A, N_EDGES - e0);

    for (int i = t; i < NBINS; i += 256) { lhist[i] = 0; lcur[i] = 0; }
    __syncthreads();

    int      mybin[TILE_A / 256];
    unsigned myval[TILE_A / 256];
    #pragma unroll
    for (int j = 0; j < TILE_A / 256; ++j) {
        const int idx = t + j * 256;
        if (idx < n) {
            const int s = ei[e0 + idx];
            const int d = ei[N_EDGES + e0 + idx];
            mybin[j] = d >> BIN_SHIFT;
            myval[j] = ((unsigned)s << BIN_SHIFT) | (unsigned)(d & (BIN_NODES - 1));
            atomicAdd(&lhist[mybin[j]], 1);
        } else {
            mybin[j] = -1;
        }
    }
    __syncthreads();

    ls[t] = (t < NBINS) ? lhist[t] : 0;
    __syncthreads();
    #pragma unroll
    for (int d = 1; d < 256; d <<= 1) {
        const int add = (t >= d) ? ls[t - d] : 0;
        __syncthreads();
        ls[t] += add;
        __syncthreads();
    }
    if (t < NBINS) lbase[t] = ls[t] - lhist[t];
    __syncthreads();

    if (t < NBINS) {
        const int c = lhist[t];
        ldelta[t] = (c > 0) ? (atomicAdd(&gcur[t], c) - lbase[t]) : 0;
    }
    __syncthreads();

    #pragma unroll
    for (int j = 0; j < TILE_A / 256; ++j) {
        if (mybin[j] >= 0) {
            const int p = lbase[mybin[j]] + atomicAdd(&lcur[mybin[j]], 1);
            staged[p] = myval[j];
            sbin[p]   = (unsigned char)mybin[j];
        }
    }
    __syncthreads();

    for (int p = t; p < n; p += 256)
        binned[p + ldelta[sbin[p]]] = staged[p];
}

// ---------------------------------------------------------------------------
// Pass B: binsort. One block per bin: per-node degrees in LDS, writes the
// off[] segment, LDS-sorts entries into final CSR order, streams out.
// ---------------------------------------------------------------------------
__global__ __launch_bounds__(256) void binsort(
    const unsigned* __restrict__ binned,
    const int* __restrict__ binbase,
    int* __restrict__ off,
    int* __restrict__ slot)
{
    __shared__ int lhist[BIN_NODES];
    __shared__ int lofs[BIN_NODES];
    __shared__ int lcur[BIN_NODES];
    __shared__ int ls[256];
    __shared__ int sseg[CAP_B];

    const int b     = blockIdx.x;
    const int node0 = b << BIN_SHIFT;
    const int nloc  = min(BIN_NODES, N_NODES - node0);
    const int rbase = binbase[b];
    const int cnt   = binbase[b + 1] - rbase;
    const int t     = threadIdx.x;

    for (int i = t; i < BIN_NODES; i += 256) { lhist[i] = 0; lcur[i] = 0; }
    __syncthreads();

    for (int p = t; p < cnt; p += 256)
        atomicAdd(&lhist[binned[rbase + p] & (BIN_NODES - 1)], 1);
    __syncthreads();

    const int a0 = lhist[2 * t];
    const int a1 = lhist[2 * t + 1];
    const int ps = a0 + a1;
    ls[t] = ps;
    __syncthreads();
    #pragma unroll
    for (int d = 1; d < 256; d <<= 1) {
        const int add = (t >= d) ? ls[t - d] : 0;
        __syncthreads();
        ls[t] += add;
        __syncthreads();
    }
    const int pbase = ls[t] - ps;
    lofs[2 * t]     = pbase;
    lofs[2 * t + 1] = pbase + a0;
    __syncthreads();

    for (int i = t; i < nloc; i += 256)
        off[node0 + i] = rbase + lofs[i];
    if (b == NBINS - 1 && t == 0) off[N_NODES] = N_EDGES;

    if (cnt <= CAP_B) {
        for (int p = t; p < cnt; p += 256) {
            const unsigned v = binned[rbase + p];
            const int dl  = v & (BIN_NODES - 1);
            const int rel = lofs[dl] + atomicAdd(&lcur[dl], 1);
            sseg[rel] = (int)(v >> BIN_SHIFT);
        }
        __syncthreads();
        for (int p = t; p < cnt; p += 256)
            slot[rbase + p] = sseg[p];
    } else {
        for (int p = t; p < cnt; p += 256) {
            const unsigned v = binned[rbase + p];
            const int dl  = v & (BIN_NODES - 1);
            const int rel = lofs[dl] + atomicAdd(&lcur[dl], 1);
            slot[rbase + rel] = (int)(v >> BIN_SHIFT);
        }
    }
}

// ---------------------------------------------------------------------------
// gather8: 8 nodes per wave, 8 lanes per node (g = lane>>3 node subgroup,
// c = lane&7 dim-chunk). Each lane exclusively owns dims c*8..c*8+7 of its
// node -> NO cross-lane reduce. 8 row loads in flight per group (64/wave),
// degree-independent. Epilogue: h = x + acc -> one uint4 store per lane.
// ---------------------------------------------------------------------------
__global__ __launch_bounds__(256) void gather8(
    const float* __restrict__ x,
    const unsigned char* __restrict__ rx,    // bf16 rows, 128 B each
    const int*   __restrict__ off,
    const int*   __restrict__ slot,
    unsigned*    __restrict__ hbuf)
{
    const int wave = (blockIdx.x * blockDim.x + threadIdx.x) >> 6;
    const int lane = threadIdx.x & 63;
    const int g    = lane >> 3;
    const int c    = lane & 7;
    const int node = wave * 8 + g;          // N_NODES % 8 == 0: always valid

    const int beg = off[node];
    const int end = off[node + 1];

    float acc[8];
    #pragma unroll
    for (int e = 0; e < 8; ++e) acc[e] = 0.f;

    for (int kb = beg; kb < end; kb += 8) {
        const int sv = (kb + c < end) ? slot[kb + c] : 0;

        int srcs[8];
        #pragma unroll
        for (int j = 0; j < 8; ++j) {
            const int s = __shfl(sv, g * 8 + j, 64);
            srcs[j] = (kb + j < end) ? s : 0;
        }
        uint4 buf[8];
        #pragma unroll
        for (int j = 0; j < 8; ++j)
            buf[j] = *reinterpret_cast<const uint4*>(
                rx + (size_t)srcs[j] * 128 + c * 16);
        #pragma unroll
        for (int j = 0; j < 8; ++j) {
            if (kb + j < end) {
                acc[0] += bflo(buf[j].x); acc[1] += bfhi(buf[j].x);
                acc[2] += bflo(buf[j].y); acc[3] += bfhi(buf[j].y);
                acc[4] += bflo(buf[j].z); acc[5] += bfhi(buf[j].z);
                acc[6] += bflo(buf[j].w); acc[7] += bfhi(buf[j].w);
            }
        }
    }

    const float4 x0 = *reinterpret_cast<const float4*>(
        x + (size_t)node * DIM + c * 8);
    const float4 x1 = *reinterpret_cast<const float4*>(
        x + (size_t)node * DIM + c * 8 + 4);
    uint4 o;
    o.x = f2bf(x0.x + acc[0]) | (f2bf(x0.y + acc[1]) << 16);
    o.y = f2bf(x0.z + acc[2]) | (f2bf(x0.w + acc[3]) << 16);
    o.z = f2bf(x1.x + acc[4]) | (f2bf(x1.y + acc[5]) << 16);
    o.w = f2bf(x1.z + acc[6]) | (f2bf(x1.w + acc[7]) << 16);
    reinterpret_cast<uint4*>(hbuf)[(size_t)node * 8 + c] = o;
}

// ---------------------------------------------------------------------------
// mlp_mfma: per wave, 16 nodes; two MFMA GEMMs, fused bias+relu (unchanged).
// ---------------------------------------------------------------------------
__global__ __launch_bounds__(256) void mlp_mfma(
    const unsigned* __restrict__ hbuf,       // bf16 rows, 128 B each
    const unsigned short* __restrict__ Wpk,  // prepacked B-frags
    const float* __restrict__ b1,
    const float* __restrict__ b2,
    float* __restrict__ out)
{
    __shared__ float yt[4][16 * 68];

    const int wiv  = threadIdx.x >> 6;
    const int lane = threadIdx.x & 63;
    const int wid  = blockIdx.x * 4 + wiv;
    const int r0   = wid * 16;
    if (r0 >= N_NODES) return;

    const int lrow = lane & 15;
    const int lgrp = lane >> 4;

    const int hrow = min(r0 + lrow, N_NODES - 1);
    const uint4* hrowp =
        reinterpret_cast<const uint4*>((const char*)hbuf + (size_t)hrow * 128);
    union UF { uint4 u; bf16x8 v; };
    UF ha0, ha1;
    ha0.u = hrowp[lgrp];
    ha1.u = hrowp[lgrp + 4];

    const uint4* wp = reinterpret_cast<const uint4*>(Wpk);

    float* my = &yt[wiv][0];
    #pragma unroll
    for (int n = 0; n < 4; ++n) {
        const float bi = b1[n * 16 + lrow];
        f32x4 acc = {bi, bi, bi, bi};
        UF bw0, bw1;
        bw0.u = wp[(n * 2 + 0) * 64 + lane];
        bw1.u = wp[(n * 2 + 1) * 64 + lane];
        acc = __builtin_amdgcn_mfma_f32_16x16x32_bf16(ha0.v, bw0.v, acc, 0, 0, 0);
        acc = __builtin_amdgcn_mfma_f32_16x16x32_bf16(ha1.v, bw1.v, acc, 0, 0, 0);
        #pragma unroll
        for (int i = 0; i < 4; ++i)
            my[(lgrp * 4 + i) * 68 + n * 16 + lrow] = fmaxf(acc[i], 0.f);
    }

    const float* yr = &yt[wiv][lrow * 68 + lgrp * 8];
    const float4 p0 = *reinterpret_cast<const float4*>(yr + 0);
    const float4 p1 = *reinterpret_cast<const float4*>(yr + 4);
    const float4 p2 = *reinterpret_cast<const float4*>(yr + 32);
    const float4 p3 = *reinterpret_cast<const float4*>(yr + 36);

    union UB { bf16x8 v; unsigned short s[8]; };
    UB ya0, ya1;
    ya0.s[0] = (unsigned short)f2bf(p0.x); ya0.s[1] = (unsigned short)f2bf(p0.y);
    ya0.s[2] = (unsigned short)f2bf(p0.z); ya0.s[3] = (unsigned short)f2bf(p0.w);
    ya0.s[4] = (unsigned short)f2bf(p1.x); ya0.s[5] = (unsigned short)f2bf(p1.y);
    ya0.s[6] = (unsigned short)f2bf(p1.z); ya0.s[7] = (unsigned short)f2bf(p1.w);
    ya1.s[0] = (unsigned short)f2bf(p2.x); ya1.s[1] = (unsigned short)f2bf(p2.y);
    ya1.s[2] = (unsigned short)f2bf(p2.z); ya1.s[3] = (unsigned short)f2bf(p2.w);
    ya1.s[4] = (unsigned short)f2bf(p3.x); ya1.s[5] = (unsigned short)f2bf(p3.y);
    ya1.s[6] = (unsigned short)f2bf(p3.z); ya1.s[7] = (unsigned short)f2bf(p3.w);

    #pragma unroll
    for (int n = 0; n < 4; ++n) {
        const float bi = b2[n * 16 + lrow];
        f32x4 acc = {bi, bi, bi, bi};
        UF bw0, bw1;
        bw0.u = wp[(8 + n * 2 + 0) * 64 + lane];
        bw1.u = wp[(8 + n * 2 + 1) * 64 + lane];
        acc = __builtin_amdgcn_mfma_f32_16x16x32_bf16(ya0.v, bw0.v, acc, 0, 0, 0);
        acc = __builtin_amdgcn_mfma_f32_16x16x32_bf16(ya1.v, bw1.v, acc, 0, 0, 0);
        #pragma unroll
        for (int i = 0; i < 4; ++i) {
            const int r = r0 + lgrp * 4 + i;
            if (r < N_NODES)
                out[(size_t)r * DIM + n * 16 + lrow] = fmaxf(acc[i], 0.f);
        }
    }
}

// ---------------------------------------------------------------------------
extern "C" void kernel_launch(void* const* d_in, const int* in_sizes, int n_in,
                              void* d_out, int out_size, void* d_ws, size_t ws_size,
                              hipStream_t stream) {
    const float* x  = (const float*)d_in[0];
    const int*   ei = (const int*)d_in[1];
    const float* W1 = (const float*)d_in[2];
    const float* b1 = (const float*)d_in[3];
    const float* W2 = (const float*)d_in[4];
    const float* b2 = (const float*)d_in[5];
    float* out = (float*)d_out;

    // rx (relu(x) in bf16, 12.8 MB) lives in d_out; fully consumed by gather8
    // before mlp_mfma overwrites d_out.
    unsigned* rx = (unsigned*)d_out;

    // workspace (ints): off | binc | binbase | gcur | slot | hbuf | Wpk
    // binned aliases hbuf (binned dead before gather8 writes hbuf).
    int* off     = (int*)d_ws;         // N_NODES + 1 (padded to 100352)
    int* binc    = off + 100352;       // 256
    int* binbase = binc + 256;         // NBINS + 1 (padded to 256)
    int* gcur    = binbase + 256;      // 256
    int* slot    = gcur + 256;         // N_EDGES
    unsigned* hbuf   = (unsigned*)(slot + N_EDGES);   // N_NODES*DIM bf16
    unsigned* binned = hbuf;                          // N_EDGES uints (alias)
    unsigned short* Wpk =
        (unsigned short*)(hbuf + (size_t)N_NODES * 32);  // 8192 bf16

    // binc zeroed inside prep_relu (block 0) — the runtime fillBuffer
    // dispatch for a 1.5 KB memset cost ~40 µs per replay.
    prep_relu<<<(N_NODES * DIM / 4 + 255) / 256, 256, 0, stream>>>(x, rx, binc);
    wprep<<<32, 256, 0, stream>>>(W1, W2, Wpk);

    const int eblocks4 = (N_EDGES / 4 + 255) / 256;
    bincount<<<eblocks4, 256, 0, stream>>>(ei, binc);
    binscan<<<1, 256, 0, stream>>>(binc, binbase, gcur);
    binscatter<<<NBLK_A, 256, 0, stream>>>(ei, gcur, binned);
    binsort<<<NBINS, 256, 0, stream>>>(binned, binbase, off, slot);

    // 8 nodes/wave, 4 waves/block -> 32 nodes/block; 100000/32 = 3125 exact
    gather8<<<3125, 256, 0, stream>>>(
        x, (const unsigned char*)rx, off, slot, hbuf);

    mlp_mfma<<<(N_NODES + 63) / 64, 256, 0, stream>>>(
        hbuf, Wpk, b1, b2, out);
}

// Round 14
// 88.353 us; speedup vs baseline: 8.7704x; 1.4271x over previous
//
#include <hip/hip_runtime.h>

#define N_NODES 100000
#define N_EDGES 1600000
#define DIM 64

#define BIN_SHIFT 9
#define BIN_NODES 512
#define NBINS ((N_NODES + BIN_NODES - 1) / BIN_NODES)   // 196
#define CAP 10240            // per-bin region capacity: mean 8163 + 23 sigma
#define TILE_A 4096
#define NBLK_A ((N_EDGES + TILE_A - 1) / TILE_A)        // 391

#define PREP_BLOCKS (N_NODES * DIM / 4 / 256)           // 6250
#define WPREP_BLOCKS 32

typedef __attribute__((ext_vector_type(8))) short bf16x8;
typedef __attribute__((ext_vector_type(4))) float f32x4;

// ---- bf16 helpers (hand-rolled, RNE; inputs are finite) --------------------
__device__ __forceinline__ float bflo(unsigned u) { return __uint_as_float(u << 16); }
__device__ __forceinline__ float bfhi(unsigned u) { return __uint_as_float(u & 0xFFFF0000u); }
__device__ __forceinline__ unsigned f2bf(float f) {
    unsigned u = __float_as_uint(f);
    u += 0x7FFFu + ((u >> 16) & 1u);
    return u >> 16;
}

// ---------------------------------------------------------------------------
// prep: blocks [0, PREP_BLOCKS): rx = relu(x) bf16. Block 0 zeroes gcur.
// Blocks [PREP_BLOCKS, +WPREP_BLOCKS): prepack W1,W2 into MFMA B-frag order.
// (fused: saves 2 graph nodes vs separate wprep + memset)
// ---------------------------------------------------------------------------
__global__ __launch_bounds__(256) void prep_fused(
    const float* __restrict__ x, unsigned* __restrict__ rx,
    int* __restrict__ gcur,
    const float* __restrict__ W1, const float* __restrict__ W2,
    unsigned short* __restrict__ Wpk)
{
    const int blk = blockIdx.x;
    if (blk < PREP_BLOCKS) {
        if (blk == 0 && threadIdx.x < NBINS) gcur[threadIdx.x] = 0;
        const int i = blk * 256 + threadIdx.x;
        const float4 v = reinterpret_cast<const float4*>(x)[i];
        uint2 o;
        o.x = f2bf(fmaxf(v.x, 0.f)) | (f2bf(fmaxf(v.y, 0.f)) << 16);
        o.y = f2bf(fmaxf(v.z, 0.f)) | (f2bf(fmaxf(v.w, 0.f)) << 16);
        reinterpret_cast<uint2*>(rx)[i] = o;
    } else {
        const int idx = (blk - PREP_BLOCKS) * 256 + threadIdx.x;
        if (idx >= 8192) return;
        const int j    = idx & 7;
        const int lane = (idx >> 3) & 63;
        const int kk   = (idx >> 9) & 1;
        const int n    = (idx >> 10) & 3;
        const int L    = idx >> 12;
        const float* W = L ? W2 : W1;
        const int k    = kk * 32 + (lane >> 4) * 8 + j;
        const int col  = n * 16 + (lane & 15);
        Wpk[idx] = (unsigned short)f2bf(W[k * DIM + col]);
    }
}

// ---------------------------------------------------------------------------
// binscatter: block stages TILE_A edges in LDS grouped by bin (dst>>9),
// allocates one contiguous run per bin in the bin's FIXED region
// [b*CAP, b*CAP+cnt) via atomicAdd on zero-seeded gcur, streams out packed
// entries (src<<9 | dst&511). No bincount/binscan prepass needed.
// Edge loads: int4 (4 consecutive edges per thread per sweep).
// ---------------------------------------------------------------------------
__global__ __launch_bounds__(256) void binscatter(
    const int* __restrict__ ei,
    int* __restrict__ gcur,
    unsigned* __restrict__ binned)
{
    __shared__ int lhist[NBINS];
    __shared__ int lbase[NBINS];
    __shared__ int lcur[NBINS];
    __shared__ int ldelta[NBINS];
    __shared__ int ls[256];
    __shared__ unsigned staged[TILE_A];
    __shared__ unsigned char sbin[TILE_A];

    const int t  = threadIdx.x;
    const int e0 = blockIdx.x * TILE_A;
    const int n  = min(TILE_A, N_EDGES - e0);   // always a multiple of 4

    for (int i = t; i < NBINS; i += 256) { lhist[i] = 0; lcur[i] = 0; }
    __syncthreads();

    int      mybin[TILE_A / 256];
    unsigned myval[TILE_A / 256];
    #pragma unroll
    for (int q = 0; q < TILE_A / 1024; ++q) {
        const int idx4 = q * 1024 + t * 4;      // 4 consecutive edges
        if (idx4 < n) {
            const int4 s4 = *reinterpret_cast<const int4*>(ei + e0 + idx4);
            const int4 d4 = *reinterpret_cast<const int4*>(ei + N_EDGES + e0 + idx4);
            const int ss[4] = {s4.x, s4.y, s4.z, s4.w};
            const int dd[4] = {d4.x, d4.y, d4.z, d4.w};
            #pragma unroll
            for (int j = 0; j < 4; ++j) {
                mybin[q * 4 + j] = dd[j] >> BIN_SHIFT;
                myval[q * 4 + j] = ((unsigned)ss[j] << BIN_SHIFT)
                                 | (unsigned)(dd[j] & (BIN_NODES - 1));
                atomicAdd(&lhist[dd[j] >> BIN_SHIFT], 1);
            }
        } else {
            #pragma unroll
            for (int j = 0; j < 4; ++j) mybin[q * 4 + j] = -1;
        }
    }
    __syncthreads();

    ls[t] = (t < NBINS) ? lhist[t] : 0;
    __syncthreads();
    #pragma unroll
    for (int d = 1; d < 256; d <<= 1) {
        const int add = (t >= d) ? ls[t - d] : 0;
        __syncthreads();
        ls[t] += add;
        __syncthreads();
    }
    if (t < NBINS) lbase[t] = ls[t] - lhist[t];
    __syncthreads();

    // allocate run in the bin's fixed region
    if (t < NBINS) {
        const int c = lhist[t];
        ldelta[t] = (c > 0) ? (t * CAP + atomicAdd(&gcur[t], c) - lbase[t]) : 0;
    }
    __syncthreads();

    #pragma unroll
    for (int j = 0; j < TILE_A / 256; ++j) {
        if (mybin[j] >= 0) {
            const int p = lbase[mybin[j]] + atomicAdd(&lcur[mybin[j]], 1);
            staged[p] = myval[j];
            sbin[p]   = (unsigned char)mybin[j];
        }
    }
    __syncthreads();

    for (int p = t; p < n; p += 256)
        binned[p + ldelta[sbin[p]]] = staged[p];
}

// ---------------------------------------------------------------------------
// binsort: one block per bin. cnt comes from gcur[b] (no scan pass). Computes
// per-node degrees in LDS, writes start[]/deg[] (block-exclusive, coalesced),
// LDS-sorts entries into per-node order, streams slot out coalesced into the
// bin's fixed region [b*CAP, b*CAP+cnt).
// ---------------------------------------------------------------------------
__global__ __launch_bounds__(256) void binsort(
    const unsigned* __restrict__ binned,
    const int* __restrict__ gcur,
    int* __restrict__ start,
    int* __restrict__ dega,
    int* __restrict__ slot)
{
    __shared__ int lhist[BIN_NODES];
    __shared__ int lofs[BIN_NODES];
    __shared__ int lcur[BIN_NODES];
    __shared__ int ls[256];
    __shared__ int sseg[CAP];

    const int b     = blockIdx.x;
    const int node0 = b << BIN_SHIFT;
    const int nloc  = min(BIN_NODES, N_NODES - node0);
    const int rbase = b * CAP;
    const int cnt   = min(gcur[b], CAP);
    const int t     = threadIdx.x;

    for (int i = t; i < BIN_NODES; i += 256) { lhist[i] = 0; lcur[i] = 0; }
    __syncthreads();

    for (int p = t; p < cnt; p += 256)
        atomicAdd(&lhist[binned[rbase + p] & (BIN_NODES - 1)], 1);
    __syncthreads();

    const int a0 = lhist[2 * t];
    const int a1 = lhist[2 * t + 1];
    const int ps = a0 + a1;
    ls[t] = ps;
    __syncthreads();
    #pragma unroll
    for (int d = 1; d < 256; d <<= 1) {
        const int add = (t >= d) ? ls[t - d] : 0;
        __syncthreads();
        ls[t] += add;
        __syncthreads();
    }
    const int pbase = ls[t] - ps;
    lofs[2 * t]     = pbase;
    lofs[2 * t + 1] = pbase + a0;
    __syncthreads();

    for (int i = t; i < nloc; i += 256) {
        start[node0 + i] = rbase + lofs[i];
        dega[node0 + i]  = lhist[i];
    }

    for (int p = t; p < cnt; p += 256) {
        const unsigned v = binned[rbase + p];
        const int dl  = v & (BIN_NODES - 1);
        const int rel = lofs[dl] + atomicAdd(&lcur[dl], 1);
        sseg[rel] = (int)(v >> BIN_SHIFT);
    }
    __syncthreads();
    for (int p = t; p < cnt; p += 256)
        slot[rbase + p] = sseg[p];
}

// ---------------------------------------------------------------------------
// gather8: 8 nodes per wave, 8 lanes per node (g = node subgroup, c = dim
// chunk). Lane exclusively owns dims c*8..c*8+7 of its node -> no cross-lane
// reduce. 8 row loads in flight per group (64/wave). Epilogue: h = x + acc.
// ---------------------------------------------------------------------------
__global__ __launch_bounds__(256) void gather8(
    const float* __restrict__ x,
    const unsigned char* __restrict__ rx,    // bf16 rows, 128 B each
    const int*   __restrict__ start,
    const int*   __restrict__ dega,
    const int*   __restrict__ slot,
    unsigned*    __restrict__ hbuf)
{
    const int wave = (blockIdx.x * blockDim.x + threadIdx.x) >> 6;
    const int lane = threadIdx.x & 63;
    const int g    = lane >> 3;
    const int c    = lane & 7;
    const int node = wave * 8 + g;          // N_NODES % 8 == 0: always valid

    const int beg = start[node];
    const int end = beg + dega[node];

    float acc[8];
    #pragma unroll
    for (int e = 0; e < 8; ++e) acc[e] = 0.f;

    for (int kb = beg; kb < end; kb += 8) {
        const int sv = (kb + c < end) ? slot[kb + c] : 0;

        int srcs[8];
        #pragma unroll
        for (int j = 0; j < 8; ++j) {
            const int s = __shfl(sv, g * 8 + j, 64);
            srcs[j] = (kb + j < end) ? s : 0;
        }
        uint4 buf[8];
        #pragma unroll
        for (int j = 0; j < 8; ++j)
            buf[j] = *reinterpret_cast<const uint4*>(
                rx + (size_t)srcs[j] * 128 + c * 16);
        #pragma unroll
        for (int j = 0; j < 8; ++j) {
            if (kb + j < end) {
                acc[0] += bflo(buf[j].x); acc[1] += bfhi(buf[j].x);
                acc[2] += bflo(buf[j].y); acc[3] += bfhi(buf[j].y);
                acc[4] += bflo(buf[j].z); acc[5] += bfhi(buf[j].z);
                acc[6] += bflo(buf[j].w); acc[7] += bfhi(buf[j].w);
            }
        }
    }

    const float4 x0 = *reinterpret_cast<const float4*>(
        x + (size_t)node * DIM + c * 8);
    const float4 x1 = *reinterpret_cast<const float4*>(
        x + (size_t)node * DIM + c * 8 + 4);
    uint4 o;
    o.x = f2bf(x0.x + acc[0]) | (f2bf(x0.y + acc[1]) << 16);
    o.y = f2bf(x0.z + acc[2]) | (f2bf(x0.w + acc[3]) << 16);
    o.z = f2bf(x1.x + acc[4]) | (f2bf(x1.y + acc[5]) << 16);
    o.w = f2bf(x1.z + acc[6]) | (f2bf(x1.w + acc[7]) << 16);
    reinterpret_cast<uint4*>(hbuf)[(size_t)node * 8 + c] = o;
}

// ---------------------------------------------------------------------------
// mlp_mfma: per wave, 16 nodes; two MFMA GEMMs, fused bias+relu (unchanged).
// ---------------------------------------------------------------------------
__global__ __launch_bounds__(256) void mlp_mfma(
    const unsigned* __restrict__ hbuf,       // bf16 rows, 128 B each
    const unsigned short* __restrict__ Wpk,  // prepacked B-frags
    const float* __restrict__ b1,
    const float* __restrict__ b2,
    float* __restrict__ out)
{
    __shared__ float yt[4][16 * 68];

    const int wiv  = threadIdx.x >> 6;
    const int lane = threadIdx.x & 63;
    const int wid  = blockIdx.x * 4 + wiv;
    const int r0   = wid * 16;
    if (r0 >= N_NODES) return;

    const int lrow = lane & 15;
    const int lgrp = lane >> 4;

    const int hrow = min(r0 + lrow, N_NODES - 1);
    const uint4* hrowp =
        reinterpret_cast<const uint4*>((const char*)hbuf + (size_t)hrow * 128);
    union UF { uint4 u; bf16x8 v; };
    UF ha0, ha1;
    ha0.u = hrowp[lgrp];
    ha1.u = hrowp[lgrp + 4];

    const uint4* wp = reinterpret_cast<const uint4*>(Wpk);

    float* my = &yt[wiv][0];
    #pragma unroll
    for (int n = 0; n < 4; ++n) {
        const float bi = b1[n * 16 + lrow];
        f32x4 acc = {bi, bi, bi, bi};
        UF bw0, bw1;
        bw0.u = wp[(n * 2 + 0) * 64 + lane];
        bw1.u = wp[(n * 2 + 1) * 64 + lane];
        acc = __builtin_amdgcn_mfma_f32_16x16x32_bf16(ha0.v, bw0.v, acc, 0, 0, 0);
        acc = __builtin_amdgcn_mfma_f32_16x16x32_bf16(ha1.v, bw1.v, acc, 0, 0, 0);
        #pragma unroll
        for (int i = 0; i < 4; ++i)
            my[(lgrp * 4 + i) * 68 + n * 16 + lrow] = fmaxf(acc[i], 0.f);
    }

    const float* yr = &yt[wiv][lrow * 68 + lgrp * 8];
    const float4 p0 = *reinterpret_cast<const float4*>(yr + 0);
    const float4 p1 = *reinterpret_cast<const float4*>(yr + 4);
    const float4 p2 = *reinterpret_cast<const float4*>(yr + 32);
    const float4 p3 = *reinterpret_cast<const float4*>(yr + 36);

    union UB { bf16x8 v; unsigned short s[8]; };
    UB ya0, ya1;
    ya0.s[0] = (unsigned short)f2bf(p0.x); ya0.s[1] = (unsigned short)f2bf(p0.y);
    ya0.s[2] = (unsigned short)f2bf(p0.z); ya0.s[3] = (unsigned short)f2bf(p0.w);
    ya0.s[4] = (unsigned short)f2bf(p1.x); ya0.s[5] = (unsigned short)f2bf(p1.y);
    ya0.s[6] = (unsigned short)f2bf(p1.z); ya0.s[7] = (unsigned short)f2bf(p1.w);
    ya1.s[0] = (unsigned short)f2bf(p2.x); ya1.s[1] = (unsigned short)f2bf(p2.y);
    ya1.s[2] = (unsigned short)f2bf(p2.z); ya1.s[3] = (unsigned short)f2bf(p2.w);
    ya1.s[4] = (unsigned short)f2bf(p3.x); ya1.s[5] = (unsigned short)f2bf(p3.y);
    ya1.s[6] = (unsigned short)f2bf(p3.z); ya1.s[7] = (unsigned short)f2bf(p3.w);

    #pragma unroll
    for (int n = 0; n < 4; ++n) {
        const float bi = b2[n * 16 + lrow];
        f32x4 acc = {bi, bi, bi, bi};
        UF bw0, bw1;
        bw0.u = wp[(8 + n * 2 + 0) * 64 + lane];
        bw1.u = wp[(8 + n * 2 + 1) * 64 + lane];
        acc = __builtin_amdgcn_mfma_f32_16x16x32_bf16(ya0.v, bw0.v, acc, 0, 0, 0);
        acc = __builtin_amdgcn_mfma_f32_16x16x32_bf16(ya1.v, bw1.v, acc, 0, 0, 0);
        #pragma unroll
        for (int i = 0; i < 4; ++i) {
            const int r = r0 + lgrp * 4 + i;
            if (r < N_NODES)
                out[(size_t)r * DIM + n * 16 + lrow] = fmaxf(acc[i], 0.f);
        }
    }
}

// ---------------------------------------------------------------------------
extern "C" void kernel_launch(void* const* d_in, const int* in_sizes, int n_in,
                              void* d_out, int out_size, void* d_ws, size_t ws_size,
                              hipStream_t stream) {
    const float* x  = (const float*)d_in[0];
    const int*   ei = (const int*)d_in[1];
    const float* W1 = (const float*)d_in[2];
    const float* b1 = (const float*)d_in[3];
    const float* W2 = (const float*)d_in[4];
    const float* b2 = (const float*)d_in[5];
    float* out = (float*)d_out;

    // rx (relu(x) in bf16, 12.8 MB) lives in d_out; fully consumed by gather8
    // before mlp_mfma overwrites d_out.
    unsigned* rx = (unsigned*)d_out;

    // workspace: start | dega | gcur | slot | hbuf | Wpk   (~21.6 MB)
    // binned aliases hbuf (dead before gather8 writes hbuf).
    int* start = (int*)d_ws;                    // N_NODES (pad 100352)
    int* dega  = start + 100352;                // N_NODES (pad 100352)
    int* gcur  = dega + 100352;                 // NBINS (pad 256)
    int* slot  = gcur + 256;                    // NBINS*CAP = 2,007,040
    unsigned* hbuf   = (unsigned*)(slot + NBINS * CAP);  // N_NODES*32 uints
    unsigned* binned = hbuf;                    // NBINS*CAP uints (alias)
    unsigned short* Wpk =
        (unsigned short*)(hbuf + (size_t)N_NODES * 32);  // 8192 bf16

    // 5 kernels total (was 8): prep+wprep+gcur-zero fused; bincount/binscan
    // eliminated via fixed-capacity bin regions.
    prep_fused<<<PREP_BLOCKS + WPREP_BLOCKS, 256, 0, stream>>>(
        x, rx, gcur, W1, W2, Wpk);

    binscatter<<<NBLK_A, 256, 0, stream>>>(ei, gcur, binned);
    binsort<<<NBINS, 256, 0, stream>>>(binned, gcur, start, dega, slot);

    // 8 nodes/wave, 4 waves/block -> 32 nodes/block; 100000/32 = 3125 exact
    gather8<<<3125, 256, 0, stream>>>(
        x, (const unsigned char*)rx, start, dega, slot, hbuf);

    mlp_mfma<<<(N_NODES + 63) / 64, 256, 0, stream>>>(
        hbuf, Wpk, b1, b2, out);
}

// Round 15
// 80.489 us; speedup vs baseline: 9.6273x; 1.0977x over previous
//
#include <hip/hip_runtime.h>

#define N_NODES 100000
#define N_EDGES 1600000
#define DIM 64

#define BIN_SHIFT 9
#define BIN_NODES 512
#define NBINS ((N_NODES + BIN_NODES - 1) / BIN_NODES)   // 196
#define CAP 10240            // per-bin region capacity: mean 8163 + 23 sigma

#define TILE_A 8192
#define NBLK_A ((N_EDGES + TILE_A - 1) / TILE_A)        // 196
#define EPT (TILE_A / 512)                              // 16 edges/thread

#define PREP_BLOCKS (N_NODES * DIM / 4 / 256)           // 6250
#define WPREP_BLOCKS 32

typedef __attribute__((ext_vector_type(8))) short bf16x8;
typedef __attribute__((ext_vector_type(4))) float f32x4;

// ---- bf16 helpers (hand-rolled, RNE; inputs are finite) --------------------
__device__ __forceinline__ float bflo(unsigned u) { return __uint_as_float(u << 16); }
__device__ __forceinline__ float bfhi(unsigned u) { return __uint_as_float(u & 0xFFFF0000u); }
__device__ __forceinline__ unsigned f2bf(float f) {
    unsigned u = __float_as_uint(f);
    u += 0x7FFFu + ((u >> 16) & 1u);
    return u >> 16;
}

// ---------------------------------------------------------------------------
// prep: blocks [0, PREP_BLOCKS): rx = relu(x) bf16; block 0 zeroes gcur.
// Blocks [PREP_BLOCKS, +WPREP_BLOCKS): prepack W1,W2 into MFMA B-frag order.
// ---------------------------------------------------------------------------
__global__ __launch_bounds__(256) void prep_fused(
    const float* __restrict__ x, unsigned* __restrict__ rx,
    int* __restrict__ gcur,
    const float* __restrict__ W1, const float* __restrict__ W2,
    unsigned short* __restrict__ Wpk)
{
    const int blk = blockIdx.x;
    if (blk < PREP_BLOCKS) {
        if (blk == 0 && threadIdx.x < NBINS) gcur[threadIdx.x] = 0;
        const int i = blk * 256 + threadIdx.x;
        const float4 v = reinterpret_cast<const float4*>(x)[i];
        uint2 o;
        o.x = f2bf(fmaxf(v.x, 0.f)) | (f2bf(fmaxf(v.y, 0.f)) << 16);
        o.y = f2bf(fmaxf(v.z, 0.f)) | (f2bf(fmaxf(v.w, 0.f)) << 16);
        reinterpret_cast<uint2*>(rx)[i] = o;
    } else {
        const int idx = (blk - PREP_BLOCKS) * 256 + threadIdx.x;
        if (idx >= 8192) return;
        const int j    = idx & 7;
        const int lane = (idx >> 3) & 63;
        const int kk   = (idx >> 9) & 1;
        const int n    = (idx >> 10) & 3;
        const int L    = idx >> 12;
        const float* W = L ? W2 : W1;
        const int k    = kk * 32 + (lane >> 4) * 8 + j;
        const int col  = n * 16 + (lane & 15);
        Wpk[idx] = (unsigned short)f2bf(W[k * DIM + col]);
    }
}

// ---------------------------------------------------------------------------
// binscatter: 512 threads, TILE_A=8192 edges staged in LDS grouped by bin
// (dst>>9); one contiguous run per bin allocated in the bin's fixed region
// [b*CAP, ...) via atomicAdd on zero-seeded gcur; packed entries
// (src<<9 | dst&511) streamed out. int4 edge loads (4 consecutive/thread).
// ---------------------------------------------------------------------------
__global__ __launch_bounds__(512) void binscatter(
    const int* __restrict__ ei,
    int* __restrict__ gcur,
    unsigned* __restrict__ binned)
{
    __shared__ int lhist[NBINS];
    __shared__ int lbase[NBINS];
    __shared__ int lcur[NBINS];
    __shared__ int ldelta[NBINS];
    __shared__ int ls[512];
    __shared__ unsigned staged[TILE_A];
    __shared__ unsigned char sbin[TILE_A];

    const int t  = threadIdx.x;
    const int e0 = blockIdx.x * TILE_A;
    const int n  = min(TILE_A, N_EDGES - e0);   // always a multiple of 4

    for (int i = t; i < NBINS; i += 512) { lhist[i] = 0; lcur[i] = 0; }
    __syncthreads();

    int      mybin[EPT];
    unsigned myval[EPT];
    #pragma unroll
    for (int q = 0; q < EPT / 4; ++q) {
        const int idx4 = q * 2048 + t * 4;      // 4 consecutive edges
        if (idx4 < n) {
            const int4 s4 = *reinterpret_cast<const int4*>(ei + e0 + idx4);
            const int4 d4 = *reinterpret_cast<const int4*>(ei + N_EDGES + e0 + idx4);
            const int ss[4] = {s4.x, s4.y, s4.z, s4.w};
            const int dd[4] = {d4.x, d4.y, d4.z, d4.w};
            #pragma unroll
            for (int j = 0; j < 4; ++j) {
                mybin[q * 4 + j] = dd[j] >> BIN_SHIFT;
                myval[q * 4 + j] = ((unsigned)ss[j] << BIN_SHIFT)
                                 | (unsigned)(dd[j] & (BIN_NODES - 1));
                atomicAdd(&lhist[dd[j] >> BIN_SHIFT], 1);
            }
        } else {
            #pragma unroll
            for (int j = 0; j < 4; ++j) mybin[q * 4 + j] = -1;
        }
    }
    __syncthreads();

    ls[t] = (t < NBINS) ? lhist[t] : 0;
    __syncthreads();
    #pragma unroll
    for (int d = 1; d < 512; d <<= 1) {
        const int add = (t >= d) ? ls[t - d] : 0;
        __syncthreads();
        ls[t] += add;
        __syncthreads();
    }
    if (t < NBINS) lbase[t] = ls[t] - lhist[t];
    __syncthreads();

    // allocate run in the bin's fixed region
    if (t < NBINS) {
        const int c = lhist[t];
        ldelta[t] = (c > 0) ? (t * CAP + atomicAdd(&gcur[t], c) - lbase[t]) : 0;
    }
    __syncthreads();

    #pragma unroll
    for (int j = 0; j < EPT; ++j) {
        if (mybin[j] >= 0) {
            const int p = lbase[mybin[j]] + atomicAdd(&lcur[mybin[j]], 1);
            staged[p] = myval[j];
            sbin[p]   = (unsigned char)mybin[j];
        }
    }
    __syncthreads();

    for (int p = t; p < n; p += 512)
        binned[p + ldelta[sbin[p]]] = staged[p];
}

// ---------------------------------------------------------------------------
// binsort: one block per bin; cnt = gcur[b]. Per-node degrees in LDS, writes
// start[]/deg[], LDS-sorts entries into per-node order, streams slot out
// coalesced into the bin's fixed region.
// ---------------------------------------------------------------------------
__global__ __launch_bounds__(256) void binsort(
    const unsigned* __restrict__ binned,
    const int* __restrict__ gcur,
    int* __restrict__ start,
    int* __restrict__ dega,
    int* __restrict__ slot)
{
    __shared__ int lhist[BIN_NODES];
    __shared__ int lofs[BIN_NODES];
    __shared__ int lcur[BIN_NODES];
    __shared__ int ls[256];
    __shared__ int sseg[CAP];

    const int b     = blockIdx.x;
    const int node0 = b << BIN_SHIFT;
    const int nloc  = min(BIN_NODES, N_NODES - node0);
    const int rbase = b * CAP;
    const int cnt   = min(gcur[b], CAP);
    const int t     = threadIdx.x;

    for (int i = t; i < BIN_NODES; i += 256) { lhist[i] = 0; lcur[i] = 0; }
    __syncthreads();

    for (int p = t; p < cnt; p += 256)
        atomicAdd(&lhist[binned[rbase + p] & (BIN_NODES - 1)], 1);
    __syncthreads();

    const int a0 = lhist[2 * t];
    const int a1 = lhist[2 * t + 1];
    const int ps = a0 + a1;
    ls[t] = ps;
    __syncthreads();
    #pragma unroll
    for (int d = 1; d < 256; d <<= 1) {
        const int add = (t >= d) ? ls[t - d] : 0;
        __syncthreads();
        ls[t] += add;
        __syncthreads();
    }
    const int pbase = ls[t] - ps;
    lofs[2 * t]     = pbase;
    lofs[2 * t + 1] = pbase + a0;
    __syncthreads();

    for (int i = t; i < nloc; i += 256) {
        start[node0 + i] = rbase + lofs[i];
        dega[node0 + i]  = lhist[i];
    }

    for (int p = t; p < cnt; p += 256) {
        const unsigned v = binned[rbase + p];
        const int dl  = v & (BIN_NODES - 1);
        const int rel = lofs[dl] + atomicAdd(&lcur[dl], 1);
        sseg[rel] = (int)(v >> BIN_SHIFT);
    }
    __syncthreads();
    for (int p = t; p < cnt; p += 256)
        slot[rbase + p] = sseg[p];
}

// ---------------------------------------------------------------------------
// gather_mlp: FUSED gather + MLP. 512 threads = 8 waves, 64 nodes per block.
// Phase 1 (all 8 waves): gather8 layout — 8 nodes/wave, 8 lanes/node, lane
// owns dims c*8..c*8+7; 8 rows in flight; h = x + agg packed bf16 into an
// LDS tile (stride 36 uints => 16B-aligned rows, spread banks).
// Phase 2 (waves 0..3): two MFMA GEMM layers straight from the LDS h-tile
// (16 nodes/wave), bias fused in acc init, relu, Y transpose via per-wave
// yt LDS, coalesced out store. Saves the 12.8 MB hbuf write + read.
// ---------------------------------------------------------------------------
__global__ __launch_bounds__(512) void gather_mlp(
    const float* __restrict__ x,
    const unsigned char* __restrict__ rx,    // bf16 rows, 128 B each
    const int*   __restrict__ start,
    const int*   __restrict__ dega,
    const int*   __restrict__ slot,
    const unsigned short* __restrict__ Wpk,  // prepacked B-frags
    const float* __restrict__ b1,
    const float* __restrict__ b2,
    float* __restrict__ out)
{
    __shared__ unsigned ht[64 * 36];         // h tile: 64 rows x 32 uints (pad 36)
    __shared__ float yt[4][16 * 68];

    const int t    = threadIdx.x;
    const int wv   = t >> 6;
    const int lane = t & 63;
    const int g    = lane >> 3;              // node subgroup 0..7
    const int c    = lane & 7;               // dim chunk 0..7
    const int row  = wv * 8 + g;             // block-local node row 0..63
    const int node = blockIdx.x * 64 + row;

    // ---- phase 1: gather
    uint4 o = make_uint4(0u, 0u, 0u, 0u);
    if (node < N_NODES) {
        const int beg = start[node];
        const int end = beg + dega[node];

        float acc[8];
        #pragma unroll
        for (int e = 0; e < 8; ++e) acc[e] = 0.f;

        for (int kb = beg; kb < end; kb += 8) {
            const int sv = (kb + c < end) ? slot[kb + c] : 0;

            int srcs[8];
            #pragma unroll
            for (int j = 0; j < 8; ++j) {
                const int s = __shfl(sv, g * 8 + j, 64);
                srcs[j] = (kb + j < end) ? s : 0;
            }
            uint4 buf[8];
            #pragma unroll
            for (int j = 0; j < 8; ++j)
                buf[j] = *reinterpret_cast<const uint4*>(
                    rx + (size_t)srcs[j] * 128 + c * 16);
            #pragma unroll
            for (int j = 0; j < 8; ++j) {
                if (kb + j < end) {
                    acc[0] += bflo(buf[j].x); acc[1] += bfhi(buf[j].x);
                    acc[2] += bflo(buf[j].y); acc[3] += bfhi(buf[j].y);
                    acc[4] += bflo(buf[j].z); acc[5] += bfhi(buf[j].z);
                    acc[6] += bflo(buf[j].w); acc[7] += bfhi(buf[j].w);
                }
            }
        }

        const float4 x0 = *reinterpret_cast<const float4*>(
            x + (size_t)node * DIM + c * 8);
        const float4 x1 = *reinterpret_cast<const float4*>(
            x + (size_t)node * DIM + c * 8 + 4);
        o.x = f2bf(x0.x + acc[0]) | (f2bf(x0.y + acc[1]) << 16);
        o.y = f2bf(x0.z + acc[2]) | (f2bf(x0.w + acc[3]) << 16);
        o.z = f2bf(x1.x + acc[4]) | (f2bf(x1.y + acc[5]) << 16);
        o.w = f2bf(x1.z + acc[6]) | (f2bf(x1.w + acc[7]) << 16);
    }
    *reinterpret_cast<uint4*>(&ht[row * 36 + c * 4]) = o;
    __syncthreads();

    // ---- phase 2: MLP (waves 0..3 only; 16 nodes each)
    if (wv >= 4) return;

    const int lrow = lane & 15;
    const int lgrp = lane >> 4;
    const int row2 = wv * 16 + lrow;         // block-local h row

    union UF { uint4 u; bf16x8 v; };
    UF ha0, ha1;
    ha0.u = *reinterpret_cast<const uint4*>(&ht[row2 * 36 + lgrp * 4]);
    ha1.u = *reinterpret_cast<const uint4*>(&ht[row2 * 36 + 16 + lgrp * 4]);

    const uint4* wp = reinterpret_cast<const uint4*>(Wpk);

    float* my = &yt[wv][0];
    #pragma unroll
    for (int n = 0; n < 4; ++n) {
        const float bi = b1[n * 16 + lrow];
        f32x4 acc = {bi, bi, bi, bi};
        UF bw0, bw1;
        bw0.u = wp[(n * 2 + 0) * 64 + lane];
        bw1.u = wp[(n * 2 + 1) * 64 + lane];
        acc = __builtin_amdgcn_mfma_f32_16x16x32_bf16(ha0.v, bw0.v, acc, 0, 0, 0);
        acc = __builtin_amdgcn_mfma_f32_16x16x32_bf16(ha1.v, bw1.v, acc, 0, 0, 0);
        #pragma unroll
        for (int i = 0; i < 4; ++i)
            my[(lgrp * 4 + i) * 68 + n * 16 + lrow] = fmaxf(acc[i], 0.f);
    }

    const float* yr = &yt[wv][lrow * 68 + lgrp * 8];
    const float4 p0 = *reinterpret_cast<const float4*>(yr + 0);
    const float4 p1 = *reinterpret_cast<const float4*>(yr + 4);
    const float4 p2 = *reinterpret_cast<const float4*>(yr + 32);
    const float4 p3 = *reinterpret_cast<const float4*>(yr + 36);

    union UB { bf16x8 v; unsigned short s[8]; };
    UB ya0, ya1;
    ya0.s[0] = (unsigned short)f2bf(p0.x); ya0.s[1] = (unsigned short)f2bf(p0.y);
    ya0.s[2] = (unsigned short)f2bf(p0.z); ya0.s[3] = (unsigned short)f2bf(p0.w);
    ya0.s[4] = (unsigned short)f2bf(p1.x); ya0.s[5] = (unsigned short)f2bf(p1.y);
    ya0.s[6] = (unsigned short)f2bf(p1.z); ya0.s[7] = (unsigned short)f2bf(p1.w);
    ya1.s[0] = (unsigned short)f2bf(p2.x); ya1.s[1] = (unsigned short)f2bf(p2.y);
    ya1.s[2] = (unsigned short)f2bf(p2.z); ya1.s[3] = (unsigned short)f2bf(p2.w);
    ya1.s[4] = (unsigned short)f2bf(p3.x); ya1.s[5] = (unsigned short)f2bf(p3.y);
    ya1.s[6] = (unsigned short)f2bf(p3.z); ya1.s[7] = (unsigned short)f2bf(p3.w);

    #pragma unroll
    for (int n = 0; n < 4; ++n) {
        const float bi = b2[n * 16 + lrow];
        f32x4 acc = {bi, bi, bi, bi};
        UF bw0, bw1;
        bw0.u = wp[(8 + n * 2 + 0) * 64 + lane];
        bw1.u = wp[(8 + n * 2 + 1) * 64 + lane];
        acc = __builtin_amdgcn_mfma_f32_16x16x32_bf16(ya0.v, bw0.v, acc, 0, 0, 0);
        acc = __builtin_amdgcn_mfma_f32_16x16x32_bf16(ya1.v, bw1.v, acc, 0, 0, 0);
        #pragma unroll
        for (int i = 0; i < 4; ++i) {
            const int r = blockIdx.x * 64 + wv * 16 + lgrp * 4 + i;
            if (r < N_NODES)
                out[(size_t)r * DIM + n * 16 + lrow] = fmaxf(acc[i], 0.f);
        }
    }
}

// ---------------------------------------------------------------------------
extern "C" void kernel_launch(void* const* d_in, const int* in_sizes, int n_in,
                              void* d_out, int out_size, void* d_ws, size_t ws_size,
                              hipStream_t stream) {
    const float* x  = (const float*)d_in[0];
    const int*   ei = (const int*)d_in[1];
    const float* W1 = (const float*)d_in[2];
    const float* b1 = (const float*)d_in[3];
    const float* W2 = (const float*)d_in[4];
    const float* b2 = (const float*)d_in[5];
    float* out = (float*)d_out;

    // workspace: start | dega | gcur | slot | binned | rx | Wpk  (~30 MB)
    // NOTE: rx moved into d_ws — the fused gather_mlp reads rx while writing
    // out, so the old rx-in-d_out aliasing would race.
    int* start = (int*)d_ws;                    // N_NODES (pad 100352)
    int* dega  = start + 100352;                // N_NODES (pad 100352)
    int* gcur  = dega + 100352;                 // NBINS (pad 256)
    int* slot  = gcur + 256;                    // NBINS*CAP = 2,007,040
    unsigned* binned = (unsigned*)(slot + NBINS * CAP);  // NBINS*CAP
    unsigned* rx     = binned + NBINS * CAP;             // N_NODES*32 uints
    unsigned short* Wpk =
        (unsigned short*)(rx + (size_t)N_NODES * 32);    // 8192 bf16

    // 4 kernels total: prep(+wprep+gcur-zero), binscatter, binsort,
    // fused gather+MLP.
    prep_fused<<<PREP_BLOCKS + WPREP_BLOCKS, 256, 0, stream>>>(
        x, rx, gcur, W1, W2, Wpk);

    binscatter<<<NBLK_A, 512, 0, stream>>>(ei, gcur, binned);
    binsort<<<NBINS, 256, 0, stream>>>(binned, gcur, start, dega, slot);

    // 64 nodes/block; ceil(100000/64) = 1563 (last block: 32 valid nodes)
    gather_mlp<<<(N_NODES + 63) / 64, 512, 0, stream>>>(
        x, (const unsigned char*)rx, start, dega, slot, Wpk, b1, b2, out);
}

// Round 16
// 72.055 us; speedup vs baseline: 10.7542x; 1.1171x over previous
//
#include <hip/hip_runtime.h>

#define N_NODES 100000
#define N_EDGES 1600000
#define DIM 64

#define BIN_SHIFT 9
#define BIN_NODES 512
#define NBINS ((N_NODES + BIN_NODES - 1) / BIN_NODES)   // 196
#define CAP 10240            // per-bin out capacity: mean 8163 + 23 sigma

#define TILE_A 8192
#define NBLK_A ((N_EDGES + TILE_A - 1) / TILE_A)        // 196
#define EPT (TILE_A / 512)                              // 16 edges/thread

#define SCAT_BLOCKS  NBLK_A                             // 196
#define PREP_BLOCKS  (N_NODES * DIM / 4 / 512)          // 3125
#define WPREP_BLOCKS 16                                 // 8192/512

typedef __attribute__((ext_vector_type(8))) short bf16x8;
typedef __attribute__((ext_vector_type(4))) float f32x4;

// ---- bf16 helpers (hand-rolled, RNE; inputs are finite) --------------------
__device__ __forceinline__ float bflo(unsigned u) { return __uint_as_float(u << 16); }
__device__ __forceinline__ float bfhi(unsigned u) { return __uint_as_float(u & 0xFFFF0000u); }
__device__ __forceinline__ unsigned f2bf(float f) {
    unsigned u = __float_as_uint(f);
    u += 0x7FFFu + ((u >> 16) & 1u);
    return u >> 16;
}

// ---------------------------------------------------------------------------
// prep_scatter: ONE kernel, three block ranges (no inter-range dependency):
//  blocks [0, 196):        binscatter — stage TILE_A edges in LDS grouped by
//                          bin (dst>>9), write the tile BLOCK-LOCALLY to
//                          binned[blk*TILE_A ...] (pure coalesced stream; no
//                          global cursor) + per-(block,bin) (cnt,base) table.
//  blocks [196, 196+3125): rx = relu(x) bf16.
//  blocks [+16):           prepack W1,W2 into MFMA B-frag order.
// binscatter blocks come FIRST so they launch early and overlap the
// BW-heavy prep streaming with their LDS-heavy binning.
// ---------------------------------------------------------------------------
__global__ __launch_bounds__(512) void prep_scatter(
    const float* __restrict__ x, unsigned* __restrict__ rx,
    const float* __restrict__ W1, const float* __restrict__ W2,
    unsigned short* __restrict__ Wpk,
    const int* __restrict__ ei,
    unsigned* __restrict__ binned,
    int* __restrict__ tblc, int* __restrict__ tblb)
{
    __shared__ int lhist[NBINS];
    __shared__ int lbase[NBINS];
    __shared__ int lcur[NBINS];
    __shared__ int ls[512];
    __shared__ unsigned staged[TILE_A];

    const int t   = threadIdx.x;
    const int blk = blockIdx.x;

    if (blk < SCAT_BLOCKS) {
        // ---------------- binscatter ----------------
        const int e0 = blk * TILE_A;
        const int n  = min(TILE_A, N_EDGES - e0);   // multiple of 4

        for (int i = t; i < NBINS; i += 512) { lhist[i] = 0; lcur[i] = 0; }
        __syncthreads();

        int      mybin[EPT];
        unsigned myval[EPT];
        #pragma unroll
        for (int q = 0; q < EPT / 4; ++q) {
            const int idx4 = q * 2048 + t * 4;
            if (idx4 < n) {
                const int4 s4 = *reinterpret_cast<const int4*>(ei + e0 + idx4);
                const int4 d4 = *reinterpret_cast<const int4*>(ei + N_EDGES + e0 + idx4);
                const int ss[4] = {s4.x, s4.y, s4.z, s4.w};
                const int dd[4] = {d4.x, d4.y, d4.z, d4.w};
                #pragma unroll
                for (int j = 0; j < 4; ++j) {
                    mybin[q * 4 + j] = dd[j] >> BIN_SHIFT;
                    myval[q * 4 + j] = ((unsigned)ss[j] << BIN_SHIFT)
                                     | (unsigned)(dd[j] & (BIN_NODES - 1));
                    atomicAdd(&lhist[dd[j] >> BIN_SHIFT], 1);
                }
            } else {
                #pragma unroll
                for (int j = 0; j < 4; ++j) mybin[q * 4 + j] = -1;
            }
        }
        __syncthreads();

        ls[t] = (t < NBINS) ? lhist[t] : 0;
        __syncthreads();
        #pragma unroll
        for (int d = 1; d < 512; d <<= 1) {
            const int add = (t >= d) ? ls[t - d] : 0;
            __syncthreads();
            ls[t] += add;
            __syncthreads();
        }
        if (t < NBINS) lbase[t] = ls[t] - lhist[t];
        __syncthreads();

        // per-(block,bin) table (coalesced 196-int rows)
        for (int i = t; i < NBINS; i += 512) {
            tblc[blk * NBINS + i] = lhist[i];
            tblb[blk * NBINS + i] = lbase[i];
        }

        // stage grouped by bin
        #pragma unroll
        for (int j = 0; j < EPT; ++j) {
            if (mybin[j] >= 0) {
                const int p = lbase[mybin[j]] + atomicAdd(&lcur[mybin[j]], 1);
                staged[p] = myval[j];
            }
        }
        __syncthreads();

        // block-local streaming output — perfectly coalesced
        for (int p = t; p < n; p += 512)
            binned[e0 + p] = staged[p];

    } else if (blk < SCAT_BLOCKS + PREP_BLOCKS) {
        // ---------------- prep: rx = relu(x) bf16 ----------------
        const int i = (blk - SCAT_BLOCKS) * 512 + t;    // exact: 3125*512
        const float4 v = reinterpret_cast<const float4*>(x)[i];
        uint2 o;
        o.x = f2bf(fmaxf(v.x, 0.f)) | (f2bf(fmaxf(v.y, 0.f)) << 16);
        o.y = f2bf(fmaxf(v.z, 0.f)) | (f2bf(fmaxf(v.w, 0.f)) << 16);
        reinterpret_cast<uint2*>(rx)[i] = o;

    } else {
        // ---------------- wprep ----------------
        const int idx = (blk - SCAT_BLOCKS - PREP_BLOCKS) * 512 + t;
        if (idx >= 8192) return;
        const int j    = idx & 7;
        const int lane = (idx >> 3) & 63;
        const int kk   = (idx >> 9) & 1;
        const int n    = (idx >> 10) & 3;
        const int L    = idx >> 12;
        const float* W = L ? W2 : W1;
        const int k    = kk * 32 + (lane >> 4) * 8 + j;
        const int col  = n * 16 + (lane & 15);
        Wpk[idx] = (unsigned short)f2bf(W[k * DIM + col]);
    }
}

// ---------------------------------------------------------------------------
// binsort: one block per bin, table-driven. Streams the bin's 196 per-block
// runs (thread-per-run sequential), builds per-node degrees in LDS, writes
// start[]/deg[], sorts entries into per-node order in LDS, streams slot out
// coalesced into the bin's fixed output region [b*CAP ...).
// ---------------------------------------------------------------------------
__global__ __launch_bounds__(256) void binsort(
    const unsigned* __restrict__ binned,
    const int* __restrict__ tblc, const int* __restrict__ tblb,
    int* __restrict__ start,
    int* __restrict__ dega,
    int* __restrict__ slot)
{
    __shared__ int lhist[BIN_NODES];
    __shared__ int lofs[BIN_NODES];
    __shared__ int lcur[BIN_NODES];
    __shared__ int ls[256];
    __shared__ int sseg[CAP];

    const int b     = blockIdx.x;
    const int node0 = b << BIN_SHIFT;
    const int nloc  = min(BIN_NODES, N_NODES - node0);
    const int rbase = b * CAP;
    const int t     = threadIdx.x;

    for (int i = t; i < BIN_NODES; i += 256) { lhist[i] = 0; lcur[i] = 0; }
    __syncthreads();

    // hist pass over the 196 runs (thread-per-run, sequential within run)
    for (int sb = t; sb < NBLK_A; sb += 256) {
        const int cnt  = tblc[sb * NBINS + b];
        const int base = sb * TILE_A + tblb[sb * NBINS + b];
        for (int i = 0; i < cnt; ++i)
            atomicAdd(&lhist[binned[base + i] & (BIN_NODES - 1)], 1);
    }
    __syncthreads();

    // exclusive scan over 512 node counts (pair per thread)
    const int a0 = lhist[2 * t];
    const int a1 = lhist[2 * t + 1];
    const int ps = a0 + a1;
    ls[t] = ps;
    __syncthreads();
    #pragma unroll
    for (int d = 1; d < 256; d <<= 1) {
        const int add = (t >= d) ? ls[t - d] : 0;
        __syncthreads();
        ls[t] += add;
        __syncthreads();
    }
    const int pbase = ls[t] - ps;
    lofs[2 * t]     = pbase;
    lofs[2 * t + 1] = pbase + a0;
    __syncthreads();

    const int total = min(lofs[BIN_NODES - 1] + lhist[BIN_NODES - 1], CAP);

    for (int i = t; i < nloc; i += 256) {
        start[node0 + i] = rbase + lofs[i];
        dega[node0 + i]  = lhist[i];
    }

    // scatter pass: into final per-node order in LDS
    for (int sb = t; sb < NBLK_A; sb += 256) {
        const int cnt  = tblc[sb * NBINS + b];
        const int base = sb * TILE_A + tblb[sb * NBINS + b];
        for (int i = 0; i < cnt; ++i) {
            const unsigned v = binned[base + i];
            const int dl  = v & (BIN_NODES - 1);
            const int rel = lofs[dl] + atomicAdd(&lcur[dl], 1);
            if (rel < CAP) sseg[rel] = (int)(v >> BIN_SHIFT);
        }
    }
    __syncthreads();

    for (int p = t; p < total; p += 256)
        slot[rbase + p] = sseg[p];
}

// ---------------------------------------------------------------------------
// gather_mlp: fused gather + MLP, 256 threads = 4 waves, 32 nodes/block.
// Phase 1 (all 4 waves): 8 nodes/wave, 8 lanes/node, lane owns dims
// c*8..c*8+7; 8 rows in flight; h = x + agg packed bf16 into LDS ht.
// Phase 2 (waves 0..1): two MFMA GEMM layers from the LDS h-tile
// (16 nodes/wave), bias in acc init, relu, Y transpose via per-wave yt.
// 256-thread blocks: finer degree-imbalance granularity than 512.
// ---------------------------------------------------------------------------
__global__ __launch_bounds__(256) void gather_mlp(
    const float* __restrict__ x,
    const unsigned char* __restrict__ rx,    // bf16 rows, 128 B each
    const int*   __restrict__ start,
    const int*   __restrict__ dega,
    const int*   __restrict__ slot,
    const unsigned short* __restrict__ Wpk,
    const float* __restrict__ b1,
    const float* __restrict__ b2,
    float* __restrict__ out)
{
    __shared__ unsigned ht[32 * 36];         // 32 rows x 32 uints (pad 36)
    __shared__ float yt[2][16 * 68];

    const int t    = threadIdx.x;
    const int wv   = t >> 6;
    const int lane = t & 63;
    const int g    = lane >> 3;              // node subgroup 0..7
    const int c    = lane & 7;               // dim chunk 0..7
    const int row  = wv * 8 + g;             // block-local node row 0..31
    const int node = blockIdx.x * 32 + row;  // N_NODES % 32 == 0: always valid

    // ---- phase 1: gather
    {
        const int beg = start[node];
        const int end = beg + dega[node];

        float acc[8];
        #pragma unroll
        for (int e = 0; e < 8; ++e) acc[e] = 0.f;

        for (int kb = beg; kb < end; kb += 8) {
            const int sv = (kb + c < end) ? slot[kb + c] : 0;

            int srcs[8];
            #pragma unroll
            for (int j = 0; j < 8; ++j) {
                const int s = __shfl(sv, g * 8 + j, 64);
                srcs[j] = (kb + j < end) ? s : 0;
            }
            uint4 buf[8];
            #pragma unroll
            for (int j = 0; j < 8; ++j)
                buf[j] = *reinterpret_cast<const uint4*>(
                    rx + (size_t)srcs[j] * 128 + c * 16);
            #pragma unroll
            for (int j = 0; j < 8; ++j) {
                if (kb + j < end) {
                    acc[0] += bflo(buf[j].x); acc[1] += bfhi(buf[j].x);
                    acc[2] += bflo(buf[j].y); acc[3] += bfhi(buf[j].y);
                    acc[4] += bflo(buf[j].z); acc[5] += bfhi(buf[j].z);
                    acc[6] += bflo(buf[j].w); acc[7] += bfhi(buf[j].w);
                }
            }
        }

        const float4 x0 = *reinterpret_cast<const float4*>(
            x + (size_t)node * DIM + c * 8);
        const float4 x1 = *reinterpret_cast<const float4*>(
            x + (size_t)node * DIM + c * 8 + 4);
        uint4 o;
        o.x = f2bf(x0.x + acc[0]) | (f2bf(x0.y + acc[1]) << 16);
        o.y = f2bf(x0.z + acc[2]) | (f2bf(x0.w + acc[3]) << 16);
        o.z = f2bf(x1.x + acc[4]) | (f2bf(x1.y + acc[5]) << 16);
        o.w = f2bf(x1.z + acc[6]) | (f2bf(x1.w + acc[7]) << 16);
        *reinterpret_cast<uint4*>(&ht[row * 36 + c * 4]) = o;
    }
    __syncthreads();

    // ---- phase 2: MLP (waves 0..1; 16 nodes each)
    if (wv >= 2) return;

    const int lrow = lane & 15;
    const int lgrp = lane >> 4;
    const int row2 = wv * 16 + lrow;

    union UF { uint4 u; bf16x8 v; };
    UF ha0, ha1;
    ha0.u = *reinterpret_cast<const uint4*>(&ht[row2 * 36 + lgrp * 4]);
    ha1.u = *reinterpret_cast<const uint4*>(&ht[row2 * 36 + 16 + lgrp * 4]);

    const uint4* wp = reinterpret_cast<const uint4*>(Wpk);

    float* my = &yt[wv][0];
    #pragma unroll
    for (int n = 0; n < 4; ++n) {
        const float bi = b1[n * 16 + lrow];
        f32x4 acc = {bi, bi, bi, bi};
        UF bw0, bw1;
        bw0.u = wp[(n * 2 + 0) * 64 + lane];
        bw1.u = wp[(n * 2 + 1) * 64 + lane];
        acc = __builtin_amdgcn_mfma_f32_16x16x32_bf16(ha0.v, bw0.v, acc, 0, 0, 0);
        acc = __builtin_amdgcn_mfma_f32_16x16x32_bf16(ha1.v, bw1.v, acc, 0, 0, 0);
        #pragma unroll
        for (int i = 0; i < 4; ++i)
            my[(lgrp * 4 + i) * 68 + n * 16 + lrow] = fmaxf(acc[i], 0.f);
    }

    const float* yr = &yt[wv][lrow * 68 + lgrp * 8];
    const float4 p0 = *reinterpret_cast<const float4*>(yr + 0);
    const float4 p1 = *reinterpret_cast<const float4*>(yr + 4);
    const float4 p2 = *reinterpret_cast<const float4*>(yr + 32);
    const float4 p3 = *reinterpret_cast<const float4*>(yr + 36);

    union UB { bf16x8 v; unsigned short s[8]; };
    UB ya0, ya1;
    ya0.s[0] = (unsigned short)f2bf(p0.x); ya0.s[1] = (unsigned short)f2bf(p0.y);
    ya0.s[2] = (unsigned short)f2bf(p0.z); ya0.s[3] = (unsigned short)f2bf(p0.w);
    ya0.s[4] = (unsigned short)f2bf(p1.x); ya0.s[5] = (unsigned short)f2bf(p1.y);
    ya0.s[6] = (unsigned short)f2bf(p1.z); ya0.s[7] = (unsigned short)f2bf(p1.w);
    ya1.s[0] = (unsigned short)f2bf(p2.x); ya1.s[1] = (unsigned short)f2bf(p2.y);
    ya1.s[2] = (unsigned short)f2bf(p2.z); ya1.s[3] = (unsigned short)f2bf(p2.w);
    ya1.s[4] = (unsigned short)f2bf(p3.x); ya1.s[5] = (unsigned short)f2bf(p3.y);
    ya1.s[6] = (unsigned short)f2bf(p3.z); ya1.s[7] = (unsigned short)f2bf(p3.w);

    #pragma unroll
    for (int n = 0; n < 4; ++n) {
        const float bi = b2[n * 16 + lrow];
        f32x4 acc = {bi, bi, bi, bi};
        UF bw0, bw1;
        bw0.u = wp[(8 + n * 2 + 0) * 64 + lane];
        bw1.u = wp[(8 + n * 2 + 1) * 64 + lane];
        acc = __builtin_amdgcn_mfma_f32_16x16x32_bf16(ya0.v, bw0.v, acc, 0, 0, 0);
        acc = __builtin_amdgcn_mfma_f32_16x16x32_bf16(ya1.v, bw1.v, acc, 0, 0, 0);
        const int r = blockIdx.x * 32 + wv * 16 + lgrp * 4;
        #pragma unroll
        for (int i = 0; i < 4; ++i)
            out[(size_t)(r + i) * DIM + n * 16 + lrow] = fmaxf(acc[i], 0.f);
    }
}

// ---------------------------------------------------------------------------
extern "C" void kernel_launch(void* const* d_in, const int* in_sizes, int n_in,
                              void* d_out, int out_size, void* d_ws, size_t ws_size,
                              hipStream_t stream) {
    const float* x  = (const float*)d_in[0];
    const int*   ei = (const int*)d_in[1];
    const float* W1 = (const float*)d_in[2];
    const float* b1 = (const float*)d_in[3];
    const float* W2 = (const float*)d_in[4];
    const float* b2 = (const float*)d_in[5];
    float* out = (float*)d_out;

    // workspace: start | dega | tblc | tblb | slot | binned | rx | Wpk (~29 MB)
    int* start = (int*)d_ws;                       // N_NODES (pad 100352)
    int* dega  = start + 100352;                   // N_NODES (pad 100352)
    int* tblc  = dega + 100352;                    // 196*196 (pad 40960)
    int* tblb  = tblc + 40960;                     // 196*196 (pad 40960)
    int* slot  = tblb + 40960;                     // NBINS*CAP = 2,007,040
    unsigned* binned = (unsigned*)(slot + NBINS * CAP);  // NBLK_A*TILE_A
    unsigned* rx     = binned + NBLK_A * TILE_A;         // N_NODES*32 uints
    unsigned short* Wpk =
        (unsigned short*)(rx + (size_t)N_NODES * 32);    // 8192 bf16

    // 3 kernels: fused prep+wprep+binscatter, table-driven binsort,
    // fused gather+MLP.
    prep_scatter<<<SCAT_BLOCKS + PREP_BLOCKS + WPREP_BLOCKS, 512, 0, stream>>>(
        x, rx, W1, W2, Wpk, ei, binned, tblc, tblb);

    binsort<<<NBINS, 256, 0, stream>>>(binned, tblc, tblb, start, dega, slot);

    // 32 nodes/block; 100000/32 = 3125 exact
    gather_mlp<<<3125, 256, 0, stream>>>(
        x, (const unsigned char*)rx, start, dega, slot, Wpk, b1, b2, out);
}

// Round 17
// 66.609 us; speedup vs baseline: 11.6334x; 1.0818x over previous
//
#include <hip/hip_runtime.h>

#define N_NODES 100000
#define N_EDGES 1600000
#define DIM 64

#define BIN_SHIFT 9
#define BIN_NODES 512
#define NBINS ((N_NODES + BIN_NODES - 1) / BIN_NODES)   // 196
#define CAP 10240            // per-bin out capacity: mean 8163 + 23 sigma

#define TILE_A 8192
#define NBLK_A ((N_EDGES + TILE_A - 1) / TILE_A)        // 196
#define EPT (TILE_A / 512)                              // 16 edges/thread

#define SCAT_BLOCKS  NBLK_A                             // 196
#define PREP_BLOCKS  (N_NODES * DIM / 4 / 512)          // 3125
#define WPREP_BLOCKS 16                                 // 8192/512

typedef __attribute__((ext_vector_type(8))) short bf16x8;
typedef __attribute__((ext_vector_type(4))) float f32x4;

// ---- bf16 helpers (hand-rolled, RNE; inputs are finite) --------------------
__device__ __forceinline__ float bflo(unsigned u) { return __uint_as_float(u << 16); }
__device__ __forceinline__ float bfhi(unsigned u) { return __uint_as_float(u & 0xFFFF0000u); }
__device__ __forceinline__ unsigned f2bf(float f) {
    unsigned u = __float_as_uint(f);
    u += 0x7FFFu + ((u >> 16) & 1u);
    return u >> 16;
}

// ---------------------------------------------------------------------------
// prep_scatter: ONE kernel, three block ranges (unchanged from R16):
//  blocks [0,196): binscatter — block-local binned runs + (cnt,base) table.
//  blocks [196, +3125): rx = relu(x) bf16.
//  blocks [+16): W prepack.
// ---------------------------------------------------------------------------
__global__ __launch_bounds__(512) void prep_scatter(
    const float* __restrict__ x, unsigned* __restrict__ rx,
    const float* __restrict__ W1, const float* __restrict__ W2,
    unsigned short* __restrict__ Wpk,
    const int* __restrict__ ei,
    unsigned* __restrict__ binned,
    int* __restrict__ tblc, int* __restrict__ tblb)
{
    __shared__ int lhist[NBINS];
    __shared__ int lbase[NBINS];
    __shared__ int lcur[NBINS];
    __shared__ int ls[512];
    __shared__ unsigned staged[TILE_A];

    const int t   = threadIdx.x;
    const int blk = blockIdx.x;

    if (blk < SCAT_BLOCKS) {
        const int e0 = blk * TILE_A;
        const int n  = min(TILE_A, N_EDGES - e0);   // multiple of 4

        for (int i = t; i < NBINS; i += 512) { lhist[i] = 0; lcur[i] = 0; }
        __syncthreads();

        int      mybin[EPT];
        unsigned myval[EPT];
        #pragma unroll
        for (int q = 0; q < EPT / 4; ++q) {
            const int idx4 = q * 2048 + t * 4;
            if (idx4 < n) {
                const int4 s4 = *reinterpret_cast<const int4*>(ei + e0 + idx4);
                const int4 d4 = *reinterpret_cast<const int4*>(ei + N_EDGES + e0 + idx4);
                const int ss[4] = {s4.x, s4.y, s4.z, s4.w};
                const int dd[4] = {d4.x, d4.y, d4.z, d4.w};
                #pragma unroll
                for (int j = 0; j < 4; ++j) {
                    mybin[q * 4 + j] = dd[j] >> BIN_SHIFT;
                    myval[q * 4 + j] = ((unsigned)ss[j] << BIN_SHIFT)
                                     | (unsigned)(dd[j] & (BIN_NODES - 1));
                    atomicAdd(&lhist[dd[j] >> BIN_SHIFT], 1);
                }
            } else {
                #pragma unroll
                for (int j = 0; j < 4; ++j) mybin[q * 4 + j] = -1;
            }
        }
        __syncthreads();

        ls[t] = (t < NBINS) ? lhist[t] : 0;
        __syncthreads();
        #pragma unroll
        for (int d = 1; d < 512; d <<= 1) {
            const int add = (t >= d) ? ls[t - d] : 0;
            __syncthreads();
            ls[t] += add;
            __syncthreads();
        }
        if (t < NBINS) lbase[t] = ls[t] - lhist[t];
        __syncthreads();

        for (int i = t; i < NBINS; i += 512) {
            tblc[blk * NBINS + i] = lhist[i];
            tblb[blk * NBINS + i] = lbase[i];
        }

        #pragma unroll
        for (int j = 0; j < EPT; ++j) {
            if (mybin[j] >= 0) {
                const int p = lbase[mybin[j]] + atomicAdd(&lcur[mybin[j]], 1);
                staged[p] = myval[j];
            }
        }
        __syncthreads();

        for (int p = t; p < n; p += 512)
            binned[e0 + p] = staged[p];

    } else if (blk < SCAT_BLOCKS + PREP_BLOCKS) {
        const int i = (blk - SCAT_BLOCKS) * 512 + t;    // exact: 3125*512
        const float4 v = reinterpret_cast<const float4*>(x)[i];
        uint2 o;
        o.x = f2bf(fmaxf(v.x, 0.f)) | (f2bf(fmaxf(v.y, 0.f)) << 16);
        o.y = f2bf(fmaxf(v.z, 0.f)) | (f2bf(fmaxf(v.w, 0.f)) << 16);
        reinterpret_cast<uint2*>(rx)[i] = o;

    } else {
        const int idx = (blk - SCAT_BLOCKS - PREP_BLOCKS) * 512 + t;
        if (idx >= 8192) return;
        const int j    = idx & 7;
        const int lane = (idx >> 3) & 63;
        const int kk   = (idx >> 9) & 1;
        const int n    = (idx >> 10) & 3;
        const int L    = idx >> 12;
        const float* W = L ? W2 : W1;
        const int k    = kk * 32 + (lane >> 4) * 8 + j;
        const int col  = n * 16 + (lane & 15);
        Wpk[idx] = (unsigned short)f2bf(W[k * DIM + col]);
    }
}

// ---------------------------------------------------------------------------
// binsort (restructured): ONE global read of the bin's entries via
// binary-search-indexed coalesced copy into LDS staged[] (all 512 threads,
// all loads independent/in flight — replaces the thread-per-run pattern of
// 42-deep serialized ~500cy load chains). Hist + scatter passes then run
// entirely from LDS. 512 threads = thread-per-node for the scan.
// LDS ~89 KB -> 1 block/CU (grid 196 < 256 CUs, so no occupancy loss).
// ---------------------------------------------------------------------------
__global__ __launch_bounds__(512) void binsort(
    const unsigned* __restrict__ binned,
    const int* __restrict__ tblc, const int* __restrict__ tblb,
    int* __restrict__ start,
    int* __restrict__ dega,
    int* __restrict__ slot)
{
    __shared__ unsigned staged[CAP];     // 40 KB
    __shared__ int sseg[CAP];            // 40 KB
    __shared__ int lhist[BIN_NODES];     // 2 KB
    __shared__ int lofs[BIN_NODES];      // 2 KB
    __shared__ int lcur[BIN_NODES];      // 2 KB
    __shared__ int ls[512];              // 2 KB
    __shared__ int r_ofs[NBLK_A + 1];    // run offsets within bin
    __shared__ int r_base[NBLK_A];       // run global bases

    const int b     = blockIdx.x;
    const int node0 = b << BIN_SHIFT;
    const int nloc  = min(BIN_NODES, N_NODES - node0);
    const int rbase = b * CAP;
    const int t     = threadIdx.x;

    // ---- run table: load counts/bases, scan counts -> r_ofs
    const int rc = (t < NBLK_A) ? tblc[t * NBINS + b] : 0;
    if (t < NBLK_A) r_base[t] = t * TILE_A + tblb[t * NBINS + b];
    ls[t] = rc;
    __syncthreads();
    #pragma unroll
    for (int d = 1; d < 512; d <<= 1) {
        const int add = (t >= d) ? ls[t - d] : 0;
        __syncthreads();
        ls[t] += add;
        __syncthreads();
    }
    if (t < NBLK_A) r_ofs[t] = ls[t] - rc;
    if (t == NBLK_A - 1) r_ofs[NBLK_A] = ls[t];
    for (int i = t; i < BIN_NODES; i += 512) { lhist[i] = 0; lcur[i] = 0; }
    __syncthreads();

    const int cnt = min(r_ofs[NBLK_A], CAP);

    // ---- single global read: position p -> run via 8-step LDS binary search
    for (int p = t; p < cnt; p += 512) {
        int lo = 0, hi = NBLK_A - 1;
        #pragma unroll
        for (int s = 0; s < 8; ++s) {
            const int mid = (lo + hi + 1) >> 1;
            if (r_ofs[mid] <= p) lo = mid; else hi = mid - 1;
        }
        staged[p] = binned[r_base[lo] + (p - r_ofs[lo])];
    }
    __syncthreads();

    // ---- hist from LDS
    for (int p = t; p < cnt; p += 512)
        atomicAdd(&lhist[staged[p] & (BIN_NODES - 1)], 1);
    __syncthreads();

    // ---- exclusive scan over 512 node counts (thread-per-node)
    const int v = lhist[t];
    ls[t] = v;
    __syncthreads();
    #pragma unroll
    for (int d = 1; d < 512; d <<= 1) {
        const int add = (t >= d) ? ls[t - d] : 0;
        __syncthreads();
        ls[t] += add;
        __syncthreads();
    }
    lofs[t] = ls[t] - v;
    __syncthreads();

    // ---- start/dega (coalesced, block-exclusive)
    if (t < nloc) {
        start[node0 + t] = rbase + lofs[t];
        dega[node0 + t]  = lhist[t];
    }

    // ---- scatter into per-node order (LDS -> LDS)
    for (int p = t; p < cnt; p += 512) {
        const unsigned e = staged[p];
        const int dl  = e & (BIN_NODES - 1);
        const int rel = lofs[dl] + atomicAdd(&lcur[dl], 1);
        sseg[rel] = (int)(e >> BIN_SHIFT);
    }
    __syncthreads();

    // ---- stream out coalesced
    for (int p = t; p < cnt; p += 512)
        slot[rbase + p] = sseg[p];
}

// ---------------------------------------------------------------------------
// gather_mlp: fused gather + MLP, 256 threads = 4 waves, 32 nodes/block
// (unchanged from R16).
// ---------------------------------------------------------------------------
__global__ __launch_bounds__(256) void gather_mlp(
    const float* __restrict__ x,
    const unsigned char* __restrict__ rx,    // bf16 rows, 128 B each
    const int*   __restrict__ start,
    const int*   __restrict__ dega,
    const int*   __restrict__ slot,
    const unsigned short* __restrict__ Wpk,
    const float* __restrict__ b1,
    const float* __restrict__ b2,
    float* __restrict__ out)
{
    __shared__ unsigned ht[32 * 36];         // 32 rows x 32 uints (pad 36)
    __shared__ float yt[2][16 * 68];

    const int t    = threadIdx.x;
    const int wv   = t >> 6;
    const int lane = t & 63;
    const int g    = lane >> 3;              // node subgroup 0..7
    const int c    = lane & 7;               // dim chunk 0..7
    const int row  = wv * 8 + g;             // block-local node row 0..31
    const int node = blockIdx.x * 32 + row;  // N_NODES % 32 == 0: always valid

    // ---- phase 1: gather
    {
        const int beg = start[node];
        const int end = beg + dega[node];

        float acc[8];
        #pragma unroll
        for (int e = 0; e < 8; ++e) acc[e] = 0.f;

        for (int kb = beg; kb < end; kb += 8) {
            const int sv = (kb + c < end) ? slot[kb + c] : 0;

            int srcs[8];
            #pragma unroll
            for (int j = 0; j < 8; ++j) {
                const int s = __shfl(sv, g * 8 + j, 64);
                srcs[j] = (kb + j < end) ? s : 0;
            }
            uint4 buf[8];
            #pragma unroll
            for (int j = 0; j < 8; ++j)
                buf[j] = *reinterpret_cast<const uint4*>(
                    rx + (size_t)srcs[j] * 128 + c * 16);
            #pragma unroll
            for (int j = 0; j < 8; ++j) {
                if (kb + j < end) {
                    acc[0] += bflo(buf[j].x); acc[1] += bfhi(buf[j].x);
                    acc[2] += bflo(buf[j].y); acc[3] += bfhi(buf[j].y);
                    acc[4] += bflo(buf[j].z); acc[5] += bfhi(buf[j].z);
                    acc[6] += bflo(buf[j].w); acc[7] += bfhi(buf[j].w);
                }
            }
        }

        const float4 x0 = *reinterpret_cast<const float4*>(
            x + (size_t)node * DIM + c * 8);
        const float4 x1 = *reinterpret_cast<const float4*>(
            x + (size_t)node * DIM + c * 8 + 4);
        uint4 o;
        o.x = f2bf(x0.x + acc[0]) | (f2bf(x0.y + acc[1]) << 16);
        o.y = f2bf(x0.z + acc[2]) | (f2bf(x0.w + acc[3]) << 16);
        o.z = f2bf(x1.x + acc[4]) | (f2bf(x1.y + acc[5]) << 16);
        o.w = f2bf(x1.z + acc[6]) | (f2bf(x1.w + acc[7]) << 16);
        *reinterpret_cast<uint4*>(&ht[row * 36 + c * 4]) = o;
    }
    __syncthreads();

    // ---- phase 2: MLP (waves 0..1; 16 nodes each)
    if (wv >= 2) return;

    const int lrow = lane & 15;
    const int lgrp = lane >> 4;
    const int row2 = wv * 16 + lrow;

    union UF { uint4 u; bf16x8 v; };
    UF ha0, ha1;
    ha0.u = *reinterpret_cast<const uint4*>(&ht[row2 * 36 + lgrp * 4]);
    ha1.u = *reinterpret_cast<const uint4*>(&ht[row2 * 36 + 16 + lgrp * 4]);

    const uint4* wp = reinterpret_cast<const uint4*>(Wpk);

    float* my = &yt[wv][0];
    #pragma unroll
    for (int n = 0; n < 4; ++n) {
        const float bi = b1[n * 16 + lrow];
        f32x4 acc = {bi, bi, bi, bi};
        UF bw0, bw1;
        bw0.u = wp[(n * 2 + 0) * 64 + lane];
        bw1.u = wp[(n * 2 + 1) * 64 + lane];
        acc = __builtin_amdgcn_mfma_f32_16x16x32_bf16(ha0.v, bw0.v, acc, 0, 0, 0);
        acc = __builtin_amdgcn_mfma_f32_16x16x32_bf16(ha1.v, bw1.v, acc, 0, 0, 0);
        #pragma unroll
        for (int i = 0; i < 4; ++i)
            my[(lgrp * 4 + i) * 68 + n * 16 + lrow] = fmaxf(acc[i], 0.f);
    }

    const float* yr = &yt[wv][lrow * 68 + lgrp * 8];
    const float4 p0 = *reinterpret_cast<const float4*>(yr + 0);
    const float4 p1 = *reinterpret_cast<const float4*>(yr + 4);
    const float4 p2 = *reinterpret_cast<const float4*>(yr + 32);
    const float4 p3 = *reinterpret_cast<const float4*>(yr + 36);

    union UB { bf16x8 v; unsigned short s[8]; };
    UB ya0, ya1;
    ya0.s[0] = (unsigned short)f2bf(p0.x); ya0.s[1] = (unsigned short)f2bf(p0.y);
    ya0.s[2] = (unsigned short)f2bf(p0.z); ya0.s[3] = (unsigned short)f2bf(p0.w);
    ya0.s[4] = (unsigned short)f2bf(p1.x); ya0.s[5] = (unsigned short)f2bf(p1.y);
    ya0.s[6] = (unsigned short)f2bf(p1.z); ya0.s[7] = (unsigned short)f2bf(p1.w);
    ya1.s[0] = (unsigned short)f2bf(p2.x); ya1.s[1] = (unsigned short)f2bf(p2.y);
    ya1.s[2] = (unsigned short)f2bf(p2.z); ya1.s[3] = (unsigned short)f2bf(p2.w);
    ya1.s[4] = (unsigned short)f2bf(p3.x); ya1.s[5] = (unsigned short)f2bf(p3.y);
    ya1.s[6] = (unsigned short)f2bf(p3.z); ya1.s[7] = (unsigned short)f2bf(p3.w);

    #pragma unroll
    for (int n = 0; n < 4; ++n) {
        const float bi = b2[n * 16 + lrow];
        f32x4 acc = {bi, bi, bi, bi};
        UF bw0, bw1;
        bw0.u = wp[(8 + n * 2 + 0) * 64 + lane];
        bw1.u = wp[(8 + n * 2 + 1) * 64 + lane];
        acc = __builtin_amdgcn_mfma_f32_16x16x32_bf16(ya0.v, bw0.v, acc, 0, 0, 0);
        acc = __builtin_amdgcn_mfma_f32_16x16x32_bf16(ya1.v, bw1.v, acc, 0, 0, 0);
        const int r = blockIdx.x * 32 + wv * 16 + lgrp * 4;
        #pragma unroll
        for (int i = 0; i < 4; ++i)
            out[(size_t)(r + i) * DIM + n * 16 + lrow] = fmaxf(acc[i], 0.f);
    }
}

// ---------------------------------------------------------------------------
extern "C" void kernel_launch(void* const* d_in, const int* in_sizes, int n_in,
                              void* d_out, int out_size, void* d_ws, size_t ws_size,
                              hipStream_t stream) {
    const float* x  = (const float*)d_in[0];
    const int*   ei = (const int*)d_in[1];
    const float* W1 = (const float*)d_in[2];
    const float* b1 = (const float*)d_in[3];
    const float* W2 = (const float*)d_in[4];
    const float* b2 = (const float*)d_in[5];
    float* out = (float*)d_out;

    // workspace: start | dega | tblc | tblb | slot | binned | rx | Wpk (~29 MB)
    int* start = (int*)d_ws;                       // N_NODES (pad 100352)
    int* dega  = start + 100352;                   // N_NODES (pad 100352)
    int* tblc  = dega + 100352;                    // 196*196 (pad 40960)
    int* tblb  = tblc + 40960;                     // 196*196 (pad 40960)
    int* slot  = tblb + 40960;                     // NBINS*CAP = 2,007,040
    unsigned* binned = (unsigned*)(slot + NBINS * CAP);  // NBLK_A*TILE_A
    unsigned* rx     = binned + NBLK_A * TILE_A;         // N_NODES*32 uints
    unsigned short* Wpk =
        (unsigned short*)(rx + (size_t)N_NODES * 32);    // 8192 bf16

    prep_scatter<<<SCAT_BLOCKS + PREP_BLOCKS + WPREP_BLOCKS, 512, 0, stream>>>(
        x, rx, W1, W2, Wpk, ei, binned, tblc, tblb);

    binsort<<<NBINS, 512, 0, stream>>>(binned, tblc, tblb, start, dega, slot);

    // 32 nodes/block; 100000/32 = 3125 exact
    gather_mlp<<<3125, 256, 0, stream>>>(
        x, (const unsigned char*)rx, start, dega, slot, Wpk, b1, b2, out);
}